// Round 15
// baseline (3538.179 us; speedup 1.0000x reference)
//
#include <hip/hip_runtime.h>
#include <stdint.h>
#include <stddef.h>

#define B_  64
#define T_  256
#define H_  1024
#define AS_ 128
#define L_  3

typedef __attribute__((ext_vector_type(8))) short bf16x8;
typedef __attribute__((ext_vector_type(4))) float f32x4;
typedef __attribute__((ext_vector_type(4))) unsigned u32x4;

__device__ __forceinline__ unsigned short f2bf(float f) {
  union { float f; unsigned u; } x; x.f = f;
  unsigned r = x.u + 0x7fffu + ((x.u >> 16) & 1u);   // RNE
  return (unsigned short)(r >> 16);
}
__device__ __forceinline__ float bf2f(unsigned short s) {
  union { unsigned u; float f; } x; x.u = ((unsigned)s) << 16; return x.f;
}
__device__ __forceinline__ float sigmf(float x) { return 1.0f / (1.0f + __expf(-x)); }
__device__ __forceinline__ float tanh_f(float x) {
  x = fminf(fmaxf(x, -15.0f), 15.0f);
  float e = __expf(2.0f * x);
  return (e - 1.0f) / (e + 1.0f);
}

// ---- device-coherent (MALL) accessors: relaxed agent atomics — proven R2..R14 ----
__device__ __forceinline__ void st_u16_cc(unsigned short* p, unsigned short v) {
  __hip_atomic_store(p, v, __ATOMIC_RELAXED, __HIP_MEMORY_SCOPE_AGENT);
}
__device__ __forceinline__ void st_u32_cc(unsigned* p, unsigned v) {
  __hip_atomic_store(p, v, __ATOMIC_RELAXED, __HIP_MEMORY_SCOPE_AGENT);
}
__device__ __forceinline__ unsigned ld_u32_cc(const unsigned* p) {
  return __hip_atomic_load(p, __ATOMIC_RELAXED, __HIP_MEMORY_SCOPE_AGENT);
}
// full-bypass loads/stores, no wait — proven R11/R13/R14
__device__ __forceinline__ u32x4 ld_b128_cc_nw(const void* p) {
  u32x4 r;
  asm volatile("global_load_dwordx4 %0, %1, off sc0 sc1" : "=v"(r) : "v"(p));
  return r;
}
__device__ __forceinline__ unsigned long long ld_b64_cc_nw(const void* p) {
  unsigned long long r;
  asm volatile("global_load_dwordx2 %0, %1, off sc0 sc1" : "=v"(r) : "v"(p));
  return r;
}
__device__ __forceinline__ void st_b128_cc_nw(void* p, u32x4 v) {
  asm volatile("global_store_dwordx4 %0, %1, off sc0 sc1" :: "v"(p), "v"(v) : "memory");
}
// counted waits with tied operands (rule #18). VMEM retires in order:
// issue {xv0,xv1,A0..3,B0..3} then vmcnt(4) => xv+A complete, B in flight.
__device__ __forceinline__ void wait_vm4_tie6(u32x4& a, u32x4& b, u32x4& c, u32x4& d,
                                              unsigned long long& x, unsigned long long& y) {
  asm volatile("s_waitcnt vmcnt(4)"
               : "+v"(a), "+v"(b), "+v"(c), "+v"(d), "+v"(x), "+v"(y) :: "memory");
  __builtin_amdgcn_sched_barrier(0);
}
__device__ __forceinline__ void wait_vm0_tie4(u32x4& a, u32x4& b, u32x4& c, u32x4& d) {
  asm volatile("s_waitcnt vmcnt(0)"
               : "+v"(a), "+v"(b), "+v"(c), "+v"(d) :: "memory");
  __builtin_amdgcn_sched_barrier(0);
}
// LDS-only barrier: keeps outstanding global loads in flight across it
__device__ __forceinline__ void lds_barrier() {
  __builtin_amdgcn_sched_barrier(0);
  asm volatile("s_waitcnt lgkmcnt(0)" ::: "memory");
  __builtin_amdgcn_sched_barrier(0);
  __builtin_amdgcn_s_barrier();
  __builtin_amdgcn_sched_barrier(0);
}

// ---------------- merged prep kernel ----------------
// segments: [zero: slots+xgprog] [Wt] [Wihb f2b] [Wh2ob f2b] [bsum]

__global__ void k_prep(unsigned* __restrict__ zp, int nzero,
                       const float* __restrict__ Wi2h, const float* __restrict__ bi2h,
                       unsigned short* __restrict__ Wt,
                       const float* __restrict__ Wih, unsigned short* __restrict__ Wihb, int nwih,
                       const float* __restrict__ Wh2o, unsigned short* __restrict__ Wh2ob,
                       const float* __restrict__ bih, const float* __restrict__ bhh,
                       float* __restrict__ bsum) {
  int i = blockIdx.x * 256 + threadIdx.x;
  if (i < nzero) { st_u32_cc(zp + i, 0u); return; }
  i -= nzero;
  if (i < AS_ * H_) { int a = i >> 10, h = i & 1023; Wt[i] = f2bf(Wi2h[h * AS_ + a] + bi2h[h]); return; }
  i -= AS_ * H_;
  if (i < nwih) { Wihb[i] = f2bf(Wih[i]); return; }
  i -= nwih;
  if (i < AS_ * H_) { Wh2ob[i] = f2bf(Wh2o[i]); return; }
  i -= AS_ * H_;
  if (i < L_ * 4 * H_) bsum[i] = bih[i] + bhh[i];
}

// gather one-hot -> xbf in T-MAJOR [T][B][H]
__global__ __launch_bounds__(128) void k_gather(const float* __restrict__ seq,
                                                const unsigned short* __restrict__ Wt,
                                                unsigned short* __restrict__ xbf) {
  __shared__ int sidx;
  const int bt = blockIdx.x, tid = threadIdx.x;
  if (seq[(size_t)bt * AS_ + tid] > 0.5f) sidx = tid;
  __syncthreads();
  const int b = bt >> 8, t = bt & 255;
  const uint4* s = (const uint4*)(Wt + (size_t)sidx * H_);
  uint4* d = (uint4*)(xbf + ((size_t)t * B_ + b) * H_);
  d[tid] = s[tid];
}

// ---------------- shared MFMA GEMM tile body ----------------
// A is t-major [T*B][K] (row = t*64+b). OUT codes:
//   2 = bf16 scan-native, cached stores (consumed next kernel)
//   3 = bf16 scan-native, BYPASS stores (consumed same kernel, cross-XCD)
//   4 = f32 out, C row remapped to b*256+t (b-major output layout)

__device__ __forceinline__ void gld16(const void* g, void* l) {
  __builtin_amdgcn_global_load_lds((const __attribute__((address_space(1))) unsigned int*)g,
                                   (__attribute__((address_space(3))) unsigned int*)l,
                                   16, 0, 0);
}

template <int OUT>
__device__ __forceinline__ void gemm_tile(const unsigned short* __restrict__ A,
                                          const unsigned short* __restrict__ Bm,
                                          const float* __restrict__ bias,
                                          void* __restrict__ Cout,
                                          int m0, int n0, int K, int N, int tid,
                                          unsigned short* As, unsigned short* Bs) {
  const int lane = tid & 63, wv = tid >> 6;
  const int wr = wv >> 1, wc = wv & 1;
  const int kg = lane >> 4, li = lane & 15;
  f32x4 acc[4][4] = {};

  for (int k0 = 0; k0 < K; k0 += 32) {
    for (int i = 0; i < 2; ++i) {
      int c0 = i * 256 + wv * 64;
      int cid = c0 + lane;
      int row = cid >> 2, lc = cid & 3;
      int sc = lc ^ ((row >> 1) & 3);
      gld16(A + (size_t)(m0 + row) * K + k0 + sc * 8, (char*)As + (size_t)c0 * 16);
      gld16(Bm + (size_t)(n0 + row) * K + k0 + sc * 8, (char*)Bs + (size_t)c0 * 16);
    }
    __syncthreads();
    bf16x8 af[4], bfm[4];
#pragma unroll
    for (int mi = 0; mi < 4; ++mi) {
      int row = wr * 64 + mi * 16 + li;
      int pc = kg ^ ((row >> 1) & 3);
      af[mi] = *(const bf16x8*)((const char*)As + row * 64 + pc * 16);
    }
#pragma unroll
    for (int ni = 0; ni < 4; ++ni) {
      int row = wc * 64 + ni * 16 + li;
      int pc = kg ^ ((row >> 1) & 3);
      bfm[ni] = *(const bf16x8*)((const char*)Bs + row * 64 + pc * 16);
    }
#pragma unroll
    for (int mi = 0; mi < 4; ++mi)
#pragma unroll
      for (int ni = 0; ni < 4; ++ni)
        acc[mi][ni] = __builtin_amdgcn_mfma_f32_16x16x32_bf16(af[mi], bfm[ni], acc[mi][ni], 0, 0, 0);
    __syncthreads();
  }

#pragma unroll
  for (int mi = 0; mi < 4; ++mi)
#pragma unroll
    for (int ni = 0; ni < 4; ++ni)
#pragma unroll
      for (int r = 0; r < 4; ++r) {
        int row = m0 + wr * 64 + mi * 16 + kg * 4 + r;
        int col = n0 + wc * 64 + ni * 16 + li;
        float v = acc[mi][ni][r] + bias[col];
        int tt = row >> 6, b = row & 63;         // A is t-major
        if (OUT == 4) {
          ((float*)Cout)[(size_t)(b * 256 + tt) * N + col] = v;
        } else {
          int g = col >> 10, u = col & 1023;
          int idx = ((tt * 4 + (b >> 4)) << 16) | ((u >> 5) << 11) |
                    ((b & 15) << 7) | ((u & 31) << 2) | g;
          if (OUT == 3) st_u16_cc(&((unsigned short*)Cout)[idx], f2bf(v));
          else          ((unsigned short*)Cout)[idx] = f2bf(v);
        }
      }
}

// ---------------- fused: scan (wgs 0..127) + persistent GEMM workers (128..255) ----
// Worker phases: (1) xg0 tiles, mt-major rounds, BYPASS C + xgprog[Wp]=round (scan
// gates on it); (2) one out-GEMM tile; (3) xg1 tiles gated on scan slots (R14).
// Scan: R13 step + xv BYPASS loads tied into vmcnt(4); poll = private slot line
// AND (layer 0 only) xgprog group (mt&3). All sync via proven cc primitives.

__global__ __launch_bounds__(256, 1) void k_fused(
    const unsigned short* __restrict__ xgs,   // scan input (scan-native)
    const float* __restrict__ Whh,            // layer-l W_hh f32
    unsigned short* __restrict__ h_pp,        // [2][B][H] bf16 (MALL)
    unsigned short* __restrict__ out_seq,     // [T][B][H] bf16 t-major, or null; gw phase-3 A
    float* __restrict__ hT, float* __restrict__ cT,
    const float* __restrict__ h0, const float* __restrict__ c0,
    unsigned* __restrict__ slots,             // [4][32][32] layer l
    const unsigned short* __restrict__ WihbN, // layer l+1 W_ih (phase 3) or null
    const float* __restrict__ bsumN,
    unsigned short* __restrict__ xgs_out,     // phase-1/3 output (= xgs)
    const unsigned short* __restrict__ xg0A,  // phase-1 A (xbf t-major) or null
    const unsigned short* __restrict__ Wihb0, // phase-1 W_ih
    const float* __restrict__ bsum0,
    unsigned* __restrict__ xgprog,            // [128] phase-1 progress, or null
    const unsigned short* __restrict__ WoutB, // phase-2 Wh2o bf16 [AS][H]
    const float* __restrict__ bout,
    float* __restrict__ outC) {               // phase-2 out f32
  __shared__ __align__(16) unsigned short Wlds[64 * 1024];   // 128 KB
  __shared__ __align__(16) unsigned short Hs[16 * 1024];     // 32 KB
  const int tid = threadIdx.x, lane = tid & 63, w = tid >> 6;
  const int wg = blockIdx.x;

  if (wg >= 128) {
    const int Wp = wg - 128;
    unsigned short* As = Wlds;
    unsigned short* Bs = Wlds + 4096;
    // ---- phase 1: xg0, mt-major rounds (round k: mt = 4k + (Wp>>5), nt = Wp&31)
    if (xg0A) {
      for (int k = 0; k < 32; ++k) {
        const int gidx = k * 128 + Wp;
        gemm_tile<3>(xg0A, Wihb0, bsum0, (void*)xgs_out,
                     (gidx >> 5) * 128, (gidx & 31) * 128, H_, 4 * H_, tid, As, Bs);
        asm volatile("s_waitcnt vmcnt(0)" ::: "memory");  // bypass C drained
        __syncthreads();
        if (tid == 0) {
          st_u32_cc(&xgprog[Wp], (unsigned)(k + 1));
          asm volatile("s_waitcnt vmcnt(0)" ::: "memory");
        }
      }
      // ---- phase 2: one out-GEMM tile (m-tile = Wp, single n-tile)
      gemm_tile<4>(xg0A, WoutB, bout, (void*)outC, Wp * 128, 0, H_, AS_, tid, As, Bs);
    }
    // ---- phase 3: xg1 gated on scan slots (R14)
    if (WihbN) {
      const int pline = (Wp & 31) * 32;
      for (int k = 0; k < 32; ++k) {
        const int gidx = Wp + k * 128;
        const int mt = gidx >> 5, nt = gidx & 31;
        const unsigned tgt = (unsigned)(2 * mt + 3);
        if (w == 0) {
          const unsigned* base = slots + (lane >> 4) * 1024 + pline + (lane & 15);
          unsigned v0, v1;
          do {
            __builtin_amdgcn_s_sleep(4);
            v0 = ld_u32_cc(base);
            v1 = ld_u32_cc(base + 16);
          } while (__any((int)((v0 < tgt) | (v1 < tgt))));
        }
        __syncthreads();
        gemm_tile<2>(out_seq, WihbN, bsumN, (void*)xgs_out,
                     mt * 128, nt * 128, H_, 4 * H_, tid, As, Bs);
      }
    }
    return;
  }

  // ---------------- scan path ----------------
  const int gb = wg >> 5, ug = wg & 31;
  const int li = lane & 15, kq = lane >> 4;
  const int b  = gb * 16 + li;
  const int u0 = ug * 32 + w * 8 + kq;
  const int u1 = u0 + 4;

  st_u16_cc(&h_pp[((size_t)B_ + b) * H_ + u0], f2bf(h0[(size_t)b * H_ + u0]));
  st_u16_cc(&h_pp[((size_t)B_ + b) * H_ + u1], f2bf(h0[(size_t)b * H_ + u1]));

  bf16x8 afr[32];
  {
    const int r0 = w * 32 + li;
    const float* wr = Whh + ((size_t)(r0 & 3) * H_ + ug * 32 + (r0 >> 2)) * H_ + kq * 8;
#pragma unroll
    for (int ks = 0; ks < 32; ++ks) {
      const float4 f0 = *(const float4*)(wr + ks * 32);
      const float4 f1 = *(const float4*)(wr + ks * 32 + 4);
      union { ushort4 a[2]; bf16x8 v; } uu_;
      uu_.a[0] = ushort4{f2bf(f0.x), f2bf(f0.y), f2bf(f0.z), f2bf(f0.w)};
      uu_.a[1] = ushort4{f2bf(f1.x), f2bf(f1.y), f2bf(f1.z), f2bf(f1.w)};
      afr[ks] = uu_.v;
    }
  }
  for (int it = 0; it < 16; ++it) {
    const int r = w * 32 + 16 + it;
    const float* wr = Whh + ((size_t)(r & 3) * H_ + ug * 32 + (r >> 2)) * H_;
#pragma unroll
    for (int j = 0; j < 4; ++j) {
      const float4 f = *(const float4*)(wr + lane * 16 + j * 4);
      ushort4 p = ushort4{f2bf(f.x), f2bf(f.y), f2bf(f.z), f2bf(f.w)};
      const int k = lane * 16 + j * 4;
      *(ushort4*)((char*)Wlds + (size_t)(w * 16 + it) * 2048 + ((2 * k) ^ ((it & 7) << 4))) = p;
    }
  }
  float cs0 = c0[(size_t)b * H_ + u0], cs1 = c0[(size_t)b * H_ + u1];
  __syncthreads();
  if (w == 3 && lane < 32) {
    st_u32_cc(&slots[gb * 1024 + lane * 32 + ug], 1u);
    asm volatile("s_waitcnt vmcnt(0)" ::: "memory");
  }

  const char* hbase = (const char*)Hs + (size_t)li * 2048;
  const char* wlb   = (const char*)Wlds + (size_t)(w * 16 + li) * 2048;
  const int fxor = (li & 7) << 4;
  const int sb = tid >> 4, seg = tid & 15;
  const int sswz = (sb & 7) << 4;
  char* drow = (char*)Hs + (size_t)sb * 2048;
  unsigned short* exch = Hs;
  const unsigned* myline = slots + gb * 1024 + ug * 32;

  for (int t = 0; t < T_; ++t) {
    // ---- poll: private slot line AND (layer0) xg0 progress of group mt&3
    if (w == 0) {
      const unsigned tgt = (unsigned)(t + 1);
      const int mt = t >> 1;
      const unsigned gtgt = (unsigned)((mt >> 2) + 1);
      const unsigned* gp = xgprog ? (xgprog + (mt & 3) * 32 + (lane & 31)) : nullptr;
      unsigned v, g;
      do {
        __builtin_amdgcn_s_sleep(1);
        v = ld_u32_cc(&myline[lane & 31]);
        g = gp ? ld_u32_cc(gp) : 0x7FFFFFFFu;
      } while (__any((int)((v < tgt) | (g < gtgt))));
    }
    __syncthreads();

    // ---- issue xv (bypass) then split-half bulk; xv+A tied at vmcnt(4)
    const size_t xb2 = ((((size_t)t * 4 + gb) << 16) | (ug << 11) | (li << 7) |
                        ((w * 8 + kq) << 2)) * 2;
    unsigned long long xar = ld_b64_cc_nw((const char*)xgs + xb2);
    unsigned long long xbr = ld_b64_cc_nw((const char*)xgs + xb2 + 32);
    const char* srcrow = (const char*)(h_pp + (size_t)((t & 1) ^ 1) * (B_ * H_) +
                                       (size_t)(gb * 16 + sb) * H_);
    u32x4 A0 = ld_b128_cc_nw(srcrow +   0 * 256 + seg * 16);
    u32x4 A1 = ld_b128_cc_nw(srcrow +   1 * 256 + seg * 16);
    u32x4 A2 = ld_b128_cc_nw(srcrow +   2 * 256 + seg * 16);
    u32x4 A3 = ld_b128_cc_nw(srcrow +   3 * 256 + seg * 16);
    u32x4 B0 = ld_b128_cc_nw(srcrow + 1024 + 0 * 256 + seg * 16);
    u32x4 B1 = ld_b128_cc_nw(srcrow + 1024 + 1 * 256 + seg * 16);
    u32x4 B2 = ld_b128_cc_nw(srcrow + 1024 + 2 * 256 + seg * 16);
    u32x4 B3 = ld_b128_cc_nw(srcrow + 1024 + 3 * 256 + seg * 16);
    wait_vm4_tie6(A0, A1, A2, A3, xar, xbr);   // xv + A retired; B in flight
    *(u32x4*)(drow + ((0 * 256 + seg * 16) ^ sswz)) = A0;
    *(u32x4*)(drow + ((1 * 256 + seg * 16) ^ sswz)) = A1;
    *(u32x4*)(drow + ((2 * 256 + seg * 16) ^ sswz)) = A2;
    *(u32x4*)(drow + ((3 * 256 + seg * 16) ^ sswz)) = A3;
    lds_barrier();

    f32x4 a0 = {0.f, 0.f, 0.f, 0.f}, a1 = {0.f, 0.f, 0.f, 0.f};
#pragma unroll
    for (int ks = 0; ks < 16; ++ks) {
      const bf16x8 bb = *(const bf16x8*)(hbase + ((ks * 64 + kq * 16) ^ fxor));
      a0 = __builtin_amdgcn_mfma_f32_16x16x32_bf16(afr[ks], bb, a0, 0, 0, 0);
      const bf16x8 aw = *(const bf16x8*)(wlb + ((ks * 64 + kq * 16) ^ fxor));
      a1 = __builtin_amdgcn_mfma_f32_16x16x32_bf16(aw, bb, a1, 0, 0, 0);
    }

    wait_vm0_tie4(B0, B1, B2, B3);
    *(u32x4*)(drow + ((1024 + 0 * 256 + seg * 16) ^ sswz)) = B0;
    *(u32x4*)(drow + ((1024 + 1 * 256 + seg * 16) ^ sswz)) = B1;
    *(u32x4*)(drow + ((1024 + 2 * 256 + seg * 16) ^ sswz)) = B2;
    *(u32x4*)(drow + ((1024 + 3 * 256 + seg * 16) ^ sswz)) = B3;
    lds_barrier();

#pragma unroll
    for (int ks = 16; ks < 32; ++ks) {
      const bf16x8 bb = *(const bf16x8*)(hbase + ((ks * 64 + kq * 16) ^ fxor));
      a0 = __builtin_amdgcn_mfma_f32_16x16x32_bf16(afr[ks], bb, a0, 0, 0, 0);
      const bf16x8 aw = *(const bf16x8*)(wlb + ((ks * 64 + kq * 16) ^ fxor));
      a1 = __builtin_amdgcn_mfma_f32_16x16x32_bf16(aw, bb, a1, 0, 0, 0);
    }

    const ushort4 xa = *(const ushort4*)&xar;
    const ushort4 xb = *(const ushort4*)&xbr;
    float h0v, h1v;
    {
      float gi = a0[0] + bf2f(xa.x), gf = a0[1] + bf2f(xa.y);
      float gg = a0[2] + bf2f(xa.z), go = a0[3] + bf2f(xa.w);
      float ci = sigmf(gf) * cs0 + sigmf(gi) * tanh_f(gg);
      cs0 = ci; h0v = sigmf(go) * tanh_f(ci);
    }
    {
      float gi = a1[0] + bf2f(xb.x), gf = a1[1] + bf2f(xb.y);
      float gg = a1[2] + bf2f(xb.z), go = a1[3] + bf2f(xb.w);
      float ci = sigmf(gf) * cs1 + sigmf(gi) * tanh_f(gg);
      cs1 = ci; h1v = sigmf(go) * tanh_f(ci);
    }
    const unsigned short hb0 = f2bf(h0v), hb1 = f2bf(h1v);

    __syncthreads();
    exch[li * 32 + w * 8 + kq]     = hb0;
    exch[li * 32 + w * 8 + kq + 4] = hb1;
    __syncthreads();

    if (t < T_ - 1) {
      const int bl = tid >> 4, j = tid & 15;
      const unsigned pack = (unsigned)exch[bl * 32 + 2 * j] |
                            ((unsigned)exch[bl * 32 + 2 * j + 1] << 16);
      st_u32_cc((unsigned*)&h_pp[((size_t)(t & 1) * B_ + gb * 16 + bl) * H_ + ug * 32 + 2 * j],
                pack);
    } else {
      hT[(size_t)b * H_ + u0] = h0v; hT[(size_t)b * H_ + u1] = h1v;
      cT[(size_t)b * H_ + u0] = cs0; cT[(size_t)b * H_ + u1] = cs1;
    }
    if (out_seq && tid < 64) {
      const int bo = tid >> 2, q = tid & 3;
      st_b128_cc_nw(&out_seq[((size_t)t * B_ + gb * 16 + bo) * H_ + ug * 32 + 8 * q],
                    *(const u32x4*)&exch[bo * 32 + 8 * q]);
    }
    asm volatile("s_waitcnt vmcnt(0)" ::: "memory");
    __syncthreads();
    if (w == 3 && lane < 32) {
      st_u32_cc(&slots[gb * 1024 + lane * 32 + ug], (unsigned)(t + 2));
      asm volatile("s_waitcnt vmcnt(0)" ::: "memory");
    }
  }
}

// ---------------- launcher ----------------

extern "C" void kernel_launch(void* const* d_in, const int* in_sizes, int n_in,
                              void* d_out, int out_size, void* d_ws, size_t ws_size,
                              hipStream_t stream) {
  const float* seq  = (const float*)d_in[0];
  const float* Wi2h = (const float*)d_in[1];
  const float* bi2h = (const float*)d_in[2];
  const float* Wih  = (const float*)d_in[3];
  const float* Whh  = (const float*)d_in[4];
  const float* bih  = (const float*)d_in[5];
  const float* bhh  = (const float*)d_in[6];
  const float* Wh2o = (const float*)d_in[7];
  const float* bh2o = (const float*)d_in[8];
  const float* h0   = (const float*)d_in[9];
  const float* c0   = (const float*)d_in[10];
  float* outF = (float*)d_out;

  size_t off = 0;
  auto nb = [&](size_t bytes) { size_t r = off; off += (bytes + 255) & ~(size_t)255; return r; };
  unsigned short* xbf   = (unsigned short*)((char*)d_ws + nb((size_t)B_ * T_ * H_ * 2));  // t-major
  unsigned short* seqA  = (unsigned short*)((char*)d_ws + nb((size_t)B_ * T_ * H_ * 2));
  unsigned short* xgs   = (unsigned short*)((char*)d_ws + nb((size_t)B_ * T_ * 4 * H_ * 2));
  unsigned short* Wihb  = (unsigned short*)((char*)d_ws + nb((size_t)L_ * 4 * H_ * H_ * 2));
  unsigned short* Wh2ob = (unsigned short*)((char*)d_ws + nb((size_t)AS_ * H_ * 2));
  unsigned short* Wt    = (unsigned short*)((char*)d_ws + nb((size_t)AS_ * H_ * 2));
  float*          bsum  = (float*)((char*)d_ws + nb((size_t)L_ * 4 * H_ * 4));
  unsigned short* h_pp  = (unsigned short*)((char*)d_ws + nb((size_t)2 * B_ * H_ * 2));
  unsigned*       slt   = (unsigned*)((char*)d_ws + nb((size_t)(L_ * 4096 + 128) * 4));
  unsigned*       xgp   = slt + L_ * 4096;
  (void)ws_size; (void)in_sizes; (void)n_in; (void)out_size;

  const int WLAYER = 4 * H_ * H_;
  const int nzero = L_ * 4096 + 128;
  const int nprep = nzero + 2 * AS_ * H_ + L_ * WLAYER + L_ * 4 * H_;

  k_prep<<<(nprep + 255) / 256, 256, 0, stream>>>(
      slt, nzero, Wi2h, bi2h, Wt, Wih, Wihb, L_ * WLAYER, Wh2o, Wh2ob, bih, bhh, bsum);
  k_gather<<<B_ * T_, 128, 0, stream>>>(seq, Wt, xbf);

  float* hT_base = outF + (size_t)B_ * T_ * AS_;
  float* cT_base = hT_base + (size_t)L_ * B_ * H_;

  // K1: scan(0) + workers {xg0 (gated-ahead), out-GEMM, xg1 (gated-behind)}
  k_fused<<<256, 256, 0, stream>>>(
      xgs, Whh, h_pp, seqA,
      hT_base, cT_base, h0, c0, slt,
      Wihb + (size_t)1 * WLAYER, bsum + (size_t)1 * 4 * H_, xgs,
      xbf, Wihb, bsum, xgp, Wh2ob, bh2o, outF);

  // K2: scan(1) + workers {xg2 gated}
  k_fused<<<256, 256, 0, stream>>>(
      xgs, Whh + (size_t)1 * WLAYER, h_pp, xbf,
      hT_base + (size_t)B_ * H_, cT_base + (size_t)B_ * H_,
      h0 + (size_t)B_ * H_, c0 + (size_t)B_ * H_, slt + (size_t)4096,
      Wihb + (size_t)2 * WLAYER, bsum + (size_t)2 * 4 * H_, xgs,
      nullptr, nullptr, nullptr, nullptr, nullptr, nullptr, nullptr);

  // K3: scan(2) only
  k_fused<<<128, 256, 0, stream>>>(
      xgs, Whh + (size_t)2 * WLAYER, h_pp, nullptr,
      hT_base + (size_t)2 * B_ * H_, cT_base + (size_t)2 * B_ * H_,
      h0 + (size_t)2 * B_ * H_, c0 + (size_t)2 * B_ * H_, slt + (size_t)2 * 4096,
      nullptr, nullptr, nullptr, nullptr, nullptr, nullptr, nullptr, nullptr, nullptr, nullptr);
}

// Round 16
// 3453.041 us; speedup vs baseline: 1.0247x; 1.0247x over previous
//
#include <hip/hip_runtime.h>
#include <stdint.h>
#include <stddef.h>

#define B_  64
#define T_  256
#define H_  1024
#define AS_ 128
#define L_  3

typedef __attribute__((ext_vector_type(8))) short bf16x8;
typedef __attribute__((ext_vector_type(4))) float f32x4;
typedef __attribute__((ext_vector_type(4))) unsigned u32x4;

__device__ __forceinline__ unsigned short f2bf(float f) {
  union { float f; unsigned u; } x; x.f = f;
  unsigned r = x.u + 0x7fffu + ((x.u >> 16) & 1u);   // RNE
  return (unsigned short)(r >> 16);
}
__device__ __forceinline__ float bf2f(unsigned short s) {
  union { unsigned u; float f; } x; x.u = ((unsigned)s) << 16; return x.f;
}
__device__ __forceinline__ float sigmf(float x) { return 1.0f / (1.0f + __expf(-x)); }
__device__ __forceinline__ float tanh_f(float x) {
  x = fminf(fmaxf(x, -15.0f), 15.0f);
  float e = __expf(2.0f * x);
  return (e - 1.0f) / (e + 1.0f);
}

// ---- device-coherent (MALL) accessors: relaxed agent atomics — proven R2..R14 ----
__device__ __forceinline__ void st_u16_cc(unsigned short* p, unsigned short v) {
  __hip_atomic_store(p, v, __ATOMIC_RELAXED, __HIP_MEMORY_SCOPE_AGENT);
}
__device__ __forceinline__ void st_u32_cc(unsigned* p, unsigned v) {
  __hip_atomic_store(p, v, __ATOMIC_RELAXED, __HIP_MEMORY_SCOPE_AGENT);
}
__device__ __forceinline__ unsigned ld_u32_cc(const unsigned* p) {
  return __hip_atomic_load(p, __ATOMIC_RELAXED, __HIP_MEMORY_SCOPE_AGENT);
}
// full-bypass loads/stores, no wait — proven R11/R13/R14
__device__ __forceinline__ u32x4 ld_b128_cc_nw(const void* p) {
  u32x4 r;
  asm volatile("global_load_dwordx4 %0, %1, off sc0 sc1" : "=v"(r) : "v"(p));
  return r;
}
__device__ __forceinline__ void st_b128_cc_nw(void* p, u32x4 v) {
  asm volatile("global_store_dwordx4 %0, %1, off sc0 sc1" :: "v"(p), "v"(v) : "memory");
}
// counted waits with tied operands (rule #18)
__device__ __forceinline__ void wait_vm4_tie4(u32x4& a, u32x4& b, u32x4& c, u32x4& d) {
  asm volatile("s_waitcnt vmcnt(4)"
               : "+v"(a), "+v"(b), "+v"(c), "+v"(d) :: "memory");
  __builtin_amdgcn_sched_barrier(0);
}
__device__ __forceinline__ void wait_vm0_tie4(u32x4& a, u32x4& b, u32x4& c, u32x4& d) {
  asm volatile("s_waitcnt vmcnt(0)"
               : "+v"(a), "+v"(b), "+v"(c), "+v"(d) :: "memory");
  __builtin_amdgcn_sched_barrier(0);
}
// LDS-only barrier: keeps outstanding global loads in flight across it
__device__ __forceinline__ void lds_barrier() {
  __builtin_amdgcn_sched_barrier(0);
  asm volatile("s_waitcnt lgkmcnt(0)" ::: "memory");
  __builtin_amdgcn_sched_barrier(0);
  __builtin_amdgcn_s_barrier();
  __builtin_amdgcn_sched_barrier(0);
}

// ---------------- merged prep kernel ----------------
// segments: [zero slots] [Wt] [Wihb f2b] [Wh2ob f2b] [bsum]

__global__ void k_prep(unsigned* __restrict__ zp, int nzero,
                       const float* __restrict__ Wi2h, const float* __restrict__ bi2h,
                       unsigned short* __restrict__ Wt,
                       const float* __restrict__ Wih, unsigned short* __restrict__ Wihb, int nwih,
                       const float* __restrict__ Wh2o, unsigned short* __restrict__ Wh2ob,
                       const float* __restrict__ bih, const float* __restrict__ bhh,
                       float* __restrict__ bsum) {
  int i = blockIdx.x * 256 + threadIdx.x;
  if (i < nzero) { st_u32_cc(zp + i, 0u); return; }
  i -= nzero;
  if (i < AS_ * H_) { int a = i >> 10, h = i & 1023; Wt[i] = f2bf(Wi2h[h * AS_ + a] + bi2h[h]); return; }
  i -= AS_ * H_;
  if (i < nwih) { Wihb[i] = f2bf(Wih[i]); return; }
  i -= nwih;
  if (i < AS_ * H_) { Wh2ob[i] = f2bf(Wh2o[i]); return; }
  i -= AS_ * H_;
  if (i < L_ * 4 * H_) bsum[i] = bih[i] + bhh[i];
}

// gather one-hot -> xbf in T-MAJOR [T][B][H]
__global__ __launch_bounds__(128) void k_gather(const float* __restrict__ seq,
                                                const unsigned short* __restrict__ Wt,
                                                unsigned short* __restrict__ xbf) {
  __shared__ int sidx;
  const int bt = blockIdx.x, tid = threadIdx.x;
  if (seq[(size_t)bt * AS_ + tid] > 0.5f) sidx = tid;
  __syncthreads();
  const int b = bt >> 8, t = bt & 255;
  const uint4* s = (const uint4*)(Wt + (size_t)sidx * H_);
  uint4* d = (uint4*)(xbf + ((size_t)t * B_ + b) * H_);
  d[tid] = s[tid];
}

// ---------------- shared MFMA GEMM tile body ----------------
// A is t-major [T*B][K] (row = t*64+b). OUT codes:
//   2 = bf16 scan-native, cached stores (consumed next kernel)
//   4 = f32 out, C row remapped to b*256+t (b-major output layout)

__device__ __forceinline__ void gld16(const void* g, void* l) {
  __builtin_amdgcn_global_load_lds((const __attribute__((address_space(1))) unsigned int*)g,
                                   (__attribute__((address_space(3))) unsigned int*)l,
                                   16, 0, 0);
}

template <int OUT>
__device__ __forceinline__ void gemm_tile(const unsigned short* __restrict__ A,
                                          const unsigned short* __restrict__ Bm,
                                          const float* __restrict__ bias,
                                          void* __restrict__ Cout,
                                          int m0, int n0, int K, int N, int tid,
                                          unsigned short* As, unsigned short* Bs) {
  const int lane = tid & 63, wv = tid >> 6;
  const int wr = wv >> 1, wc = wv & 1;
  const int kg = lane >> 4, li = lane & 15;
  f32x4 acc[4][4] = {};

  for (int k0 = 0; k0 < K; k0 += 32) {
    for (int i = 0; i < 2; ++i) {
      int c0 = i * 256 + wv * 64;
      int cid = c0 + lane;
      int row = cid >> 2, lc = cid & 3;
      int sc = lc ^ ((row >> 1) & 3);
      gld16(A + (size_t)(m0 + row) * K + k0 + sc * 8, (char*)As + (size_t)c0 * 16);
      gld16(Bm + (size_t)(n0 + row) * K + k0 + sc * 8, (char*)Bs + (size_t)c0 * 16);
    }
    __syncthreads();
    bf16x8 af[4], bfm[4];
#pragma unroll
    for (int mi = 0; mi < 4; ++mi) {
      int row = wr * 64 + mi * 16 + li;
      int pc = kg ^ ((row >> 1) & 3);
      af[mi] = *(const bf16x8*)((const char*)As + row * 64 + pc * 16);
    }
#pragma unroll
    for (int ni = 0; ni < 4; ++ni) {
      int row = wc * 64 + ni * 16 + li;
      int pc = kg ^ ((row >> 1) & 3);
      bfm[ni] = *(const bf16x8*)((const char*)Bs + row * 64 + pc * 16);
    }
#pragma unroll
    for (int mi = 0; mi < 4; ++mi)
#pragma unroll
      for (int ni = 0; ni < 4; ++ni)
        acc[mi][ni] = __builtin_amdgcn_mfma_f32_16x16x32_bf16(af[mi], bfm[ni], acc[mi][ni], 0, 0, 0);
    __syncthreads();
  }

#pragma unroll
  for (int mi = 0; mi < 4; ++mi)
#pragma unroll
    for (int ni = 0; ni < 4; ++ni)
#pragma unroll
      for (int r = 0; r < 4; ++r) {
        int row = m0 + wr * 64 + mi * 16 + kg * 4 + r;
        int col = n0 + wc * 64 + ni * 16 + li;
        float v = acc[mi][ni][r] + bias[col];
        int tt = row >> 6, b = row & 63;         // A is t-major
        if (OUT == 4) {
          ((float*)Cout)[(size_t)(b * 256 + tt) * N + col] = v;
        } else {
          int g = col >> 10, u = col & 1023;
          int idx = ((tt * 4 + (b >> 4)) << 16) | ((u >> 5) << 11) |
                    ((b & 15) << 7) | ((u & 31) << 2) | g;
          ((unsigned short*)Cout)[idx] = f2bf(v);
        }
      }
}

template <int OUT>
__global__ __launch_bounds__(256) void k_gemm(const unsigned short* __restrict__ A,
                                              const unsigned short* __restrict__ Bm,
                                              const float* __restrict__ bias,
                                              void* __restrict__ Cout,
                                              int M, int N, int K) {
  __shared__ __align__(16) unsigned short As[128 * 32];
  __shared__ __align__(16) unsigned short Bs[128 * 32];
  gemm_tile<OUT>(A, Bm, bias, Cout, blockIdx.x * 128, blockIdx.y * 128,
                 K, N, threadIdx.x, As, Bs);
}

// ---------------- fused: scan (wgs 0..127) + persistent GEMM workers (128..255) ----
// Worker phases: (1) one ungated out-GEMM tile (K1 only, xbf ready at start);
// (2) 32 xg(l+1) tiles gated on scan slots (R14). Scan = R13 step; out_seq t-major,
// bypass-written BEFORE the slot drain so slot t+2 certifies rows <= t visible.
// 256 wgs at 160KB LDS = 1 wg/CU -> all co-resident, no dispatch-order deadlock.

__global__ __launch_bounds__(256, 1) void k_fused(
    const unsigned short* __restrict__ xgs,   // scan input (scan-native)
    const float* __restrict__ Whh,            // layer-l W_hh f32
    unsigned short* __restrict__ h_pp,        // [2][B][H] bf16 (MALL)
    unsigned short* __restrict__ out_seq,     // [T][B][H] bf16 t-major, or null; gw phase-2 A
    float* __restrict__ hT, float* __restrict__ cT,
    const float* __restrict__ h0, const float* __restrict__ c0,
    unsigned* __restrict__ slots,             // [4][32][32] layer l
    const unsigned short* __restrict__ WihbN, // layer l+1 W_ih (phase 2) or null
    const float* __restrict__ bsumN,
    unsigned short* __restrict__ xgs_out,     // phase-2 output (= xgs, in-place)
    const unsigned short* __restrict__ outA,  // phase-1 A (xbf t-major) or null
    const unsigned short* __restrict__ WoutB, // phase-1 Wh2o bf16 [AS][H]
    const float* __restrict__ bout,
    float* __restrict__ outC) {               // phase-1 out f32
  __shared__ __align__(16) unsigned short Wlds[64 * 1024];   // 128 KB
  __shared__ __align__(16) unsigned short Hs[16 * 1024];     // 32 KB
  const int tid = threadIdx.x, lane = tid & 63, w = tid >> 6;
  const int wg = blockIdx.x;

  if (wg >= 128) {
    const int Wp = wg - 128;
    unsigned short* As = Wlds;
    unsigned short* Bs = Wlds + 4096;
    // ---- phase 1 (K1 only): one out-GEMM tile, ungated
    if (outA)
      gemm_tile<4>(outA, WoutB, bout, (void*)outC, Wp * 128, 0, H_, AS_, tid, As, Bs);
    // ---- phase 2: xg(l+1) gated on scan slots
    if (WihbN) {
      const int pline = (Wp & 31) * 32;
      for (int k = 0; k < 32; ++k) {
        const int gidx = Wp + k * 128;
        const int mt = gidx >> 5, nt = gidx & 31;
        const unsigned tgt = (unsigned)(2 * mt + 3);
        if (w == 0) {                         // poll 128 slots: gb=lane>>4, 2 producers/lane
          const unsigned* base = slots + (lane >> 4) * 1024 + pline + (lane & 15);
          unsigned v0, v1;
          do {
            __builtin_amdgcn_s_sleep(4);
            v0 = ld_u32_cc(base);
            v1 = ld_u32_cc(base + 16);
          } while (__any((int)((v0 < tgt) | (v1 < tgt))));
        }
        __syncthreads();
        gemm_tile<2>(out_seq, WihbN, bsumN, (void*)xgs_out,
                     mt * 128, nt * 128, H_, 4 * H_, tid, As, Bs);
      }
    }
    return;
  }

  // ---------------- scan path (R13/R14) ----------------
  const int gb = wg >> 5, ug = wg & 31;
  const int li = lane & 15, kq = lane >> 4;
  const int b  = gb * 16 + li;
  const int u0 = ug * 32 + w * 8 + kq;
  const int u1 = u0 + 4;

  st_u16_cc(&h_pp[((size_t)B_ + b) * H_ + u0], f2bf(h0[(size_t)b * H_ + u0]));
  st_u16_cc(&h_pp[((size_t)B_ + b) * H_ + u1], f2bf(h0[(size_t)b * H_ + u1]));

  bf16x8 afr[32];
  {
    const int r0 = w * 32 + li;
    const float* wr = Whh + ((size_t)(r0 & 3) * H_ + ug * 32 + (r0 >> 2)) * H_ + kq * 8;
#pragma unroll
    for (int ks = 0; ks < 32; ++ks) {
      const float4 f0 = *(const float4*)(wr + ks * 32);
      const float4 f1 = *(const float4*)(wr + ks * 32 + 4);
      union { ushort4 a[2]; bf16x8 v; } uu_;
      uu_.a[0] = ushort4{f2bf(f0.x), f2bf(f0.y), f2bf(f0.z), f2bf(f0.w)};
      uu_.a[1] = ushort4{f2bf(f1.x), f2bf(f1.y), f2bf(f1.z), f2bf(f1.w)};
      afr[ks] = uu_.v;
    }
  }
  for (int it = 0; it < 16; ++it) {
    const int r = w * 32 + 16 + it;
    const float* wr = Whh + ((size_t)(r & 3) * H_ + ug * 32 + (r >> 2)) * H_;
#pragma unroll
    for (int j = 0; j < 4; ++j) {
      const float4 f = *(const float4*)(wr + lane * 16 + j * 4);
      ushort4 p = ushort4{f2bf(f.x), f2bf(f.y), f2bf(f.z), f2bf(f.w)};
      const int k = lane * 16 + j * 4;
      *(ushort4*)((char*)Wlds + (size_t)(w * 16 + it) * 2048 + ((2 * k) ^ ((it & 7) << 4))) = p;
    }
  }
  float cs0 = c0[(size_t)b * H_ + u0], cs1 = c0[(size_t)b * H_ + u1];
  __syncthreads();
  if (w == 3 && lane < 32) {
    st_u32_cc(&slots[gb * 1024 + lane * 32 + ug], 1u);
    asm volatile("s_waitcnt vmcnt(0)" ::: "memory");
  }

  const char* hbase = (const char*)Hs + (size_t)li * 2048;
  const char* wlb   = (const char*)Wlds + (size_t)(w * 16 + li) * 2048;
  const int fxor = (li & 7) << 4;
  const int sb = tid >> 4, seg = tid & 15;
  const int sswz = (sb & 7) << 4;
  char* drow = (char*)Hs + (size_t)sb * 2048;
  unsigned short* exch = Hs;
  const unsigned* myline = slots + gb * 1024 + ug * 32;

  for (int t = 0; t < T_; ++t) {
    // xv: cached loads (xgs produced by prior dispatch's cached stores — R14-proven)
    const size_t xb2 = ((((size_t)t * 4 + gb) << 16) | (ug << 11) | (li << 7) |
                        ((w * 8 + kq) << 2)) * 2;
    const ushort4 xa = *(const ushort4*)((const char*)xgs + xb2);
    const ushort4 xb = *(const ushort4*)((const char*)xgs + xb2 + 32);

    if (w == 0) {
      const unsigned tgt = (unsigned)(t + 1);
      unsigned v;
      do {
        __builtin_amdgcn_s_sleep(1);
        v = ld_u32_cc(&myline[lane & 31]);
      } while (__any((int)(v < tgt)));
    }
    __syncthreads();

    // split-half bulk: coalesced 16B bypass loads, B half overlaps MFMA-A
    const char* srcrow = (const char*)(h_pp + (size_t)((t & 1) ^ 1) * (B_ * H_) +
                                       (size_t)(gb * 16 + sb) * H_);
    u32x4 A0 = ld_b128_cc_nw(srcrow +   0 * 256 + seg * 16);
    u32x4 A1 = ld_b128_cc_nw(srcrow +   1 * 256 + seg * 16);
    u32x4 A2 = ld_b128_cc_nw(srcrow +   2 * 256 + seg * 16);
    u32x4 A3 = ld_b128_cc_nw(srcrow +   3 * 256 + seg * 16);
    u32x4 B0 = ld_b128_cc_nw(srcrow + 1024 + 0 * 256 + seg * 16);
    u32x4 B1 = ld_b128_cc_nw(srcrow + 1024 + 1 * 256 + seg * 16);
    u32x4 B2 = ld_b128_cc_nw(srcrow + 1024 + 2 * 256 + seg * 16);
    u32x4 B3 = ld_b128_cc_nw(srcrow + 1024 + 3 * 256 + seg * 16);
    wait_vm4_tie4(A0, A1, A2, A3);
    *(u32x4*)(drow + ((0 * 256 + seg * 16) ^ sswz)) = A0;
    *(u32x4*)(drow + ((1 * 256 + seg * 16) ^ sswz)) = A1;
    *(u32x4*)(drow + ((2 * 256 + seg * 16) ^ sswz)) = A2;
    *(u32x4*)(drow + ((3 * 256 + seg * 16) ^ sswz)) = A3;
    lds_barrier();

    f32x4 a0 = {0.f, 0.f, 0.f, 0.f}, a1 = {0.f, 0.f, 0.f, 0.f};
#pragma unroll
    for (int ks = 0; ks < 16; ++ks) {
      const bf16x8 bb = *(const bf16x8*)(hbase + ((ks * 64 + kq * 16) ^ fxor));
      a0 = __builtin_amdgcn_mfma_f32_16x16x32_bf16(afr[ks], bb, a0, 0, 0, 0);
      const bf16x8 aw = *(const bf16x8*)(wlb + ((ks * 64 + kq * 16) ^ fxor));
      a1 = __builtin_amdgcn_mfma_f32_16x16x32_bf16(aw, bb, a1, 0, 0, 0);
    }

    wait_vm0_tie4(B0, B1, B2, B3);
    *(u32x4*)(drow + ((1024 + 0 * 256 + seg * 16) ^ sswz)) = B0;
    *(u32x4*)(drow + ((1024 + 1 * 256 + seg * 16) ^ sswz)) = B1;
    *(u32x4*)(drow + ((1024 + 2 * 256 + seg * 16) ^ sswz)) = B2;
    *(u32x4*)(drow + ((1024 + 3 * 256 + seg * 16) ^ sswz)) = B3;
    lds_barrier();

#pragma unroll
    for (int ks = 16; ks < 32; ++ks) {
      const bf16x8 bb = *(const bf16x8*)(hbase + ((ks * 64 + kq * 16) ^ fxor));
      a0 = __builtin_amdgcn_mfma_f32_16x16x32_bf16(afr[ks], bb, a0, 0, 0, 0);
      const bf16x8 aw = *(const bf16x8*)(wlb + ((ks * 64 + kq * 16) ^ fxor));
      a1 = __builtin_amdgcn_mfma_f32_16x16x32_bf16(aw, bb, a1, 0, 0, 0);
    }

    float h0v, h1v;
    {
      float gi = a0[0] + bf2f(xa.x), gf = a0[1] + bf2f(xa.y);
      float gg = a0[2] + bf2f(xa.z), go = a0[3] + bf2f(xa.w);
      float ci = sigmf(gf) * cs0 + sigmf(gi) * tanh_f(gg);
      cs0 = ci; h0v = sigmf(go) * tanh_f(ci);
    }
    {
      float gi = a1[0] + bf2f(xb.x), gf = a1[1] + bf2f(xb.y);
      float gg = a1[2] + bf2f(xb.z), go = a1[3] + bf2f(xb.w);
      float ci = sigmf(gf) * cs1 + sigmf(gi) * tanh_f(gg);
      cs1 = ci; h1v = sigmf(go) * tanh_f(ci);
    }
    const unsigned short hb0 = f2bf(h0v), hb1 = f2bf(h1v);

    __syncthreads();                          // all Hs MFMA reads done
    exch[li * 32 + w * 8 + kq]     = hb0;
    exch[li * 32 + w * 8 + kq + 4] = hb1;
    __syncthreads();

    if (t < T_ - 1) {
      const int bl = tid >> 4, j = tid & 15;
      const unsigned pack = (unsigned)exch[bl * 32 + 2 * j] |
                            ((unsigned)exch[bl * 32 + 2 * j + 1] << 16);
      st_u32_cc((unsigned*)&h_pp[((size_t)(t & 1) * B_ + gb * 16 + bl) * H_ + ug * 32 + 2 * j],
                pack);
    } else {
      hT[(size_t)b * H_ + u0] = h0v; hT[(size_t)b * H_ + u1] = h1v;
      cT[(size_t)b * H_ + u0] = cs0; cT[(size_t)b * H_ + u1] = cs1;
    }
    if (out_seq && tid < 64) {
      const int bo = tid >> 2, q = tid & 3;
      st_b128_cc_nw(&out_seq[((size_t)t * B_ + gb * 16 + bo) * H_ + ug * 32 + 8 * q],
                    *(const u32x4*)&exch[bo * 32 + 8 * q]);
    }
    asm volatile("s_waitcnt vmcnt(0)" ::: "memory");
    __syncthreads();                          // all publishes + out_seq ACKed
    if (w == 3 && lane < 32) {
      st_u32_cc(&slots[gb * 1024 + lane * 32 + ug], (unsigned)(t + 2));
      asm volatile("s_waitcnt vmcnt(0)" ::: "memory");
    }
  }
}

// ---------------- launcher ----------------

extern "C" void kernel_launch(void* const* d_in, const int* in_sizes, int n_in,
                              void* d_out, int out_size, void* d_ws, size_t ws_size,
                              hipStream_t stream) {
  const float* seq  = (const float*)d_in[0];
  const float* Wi2h = (const float*)d_in[1];
  const float* bi2h = (const float*)d_in[2];
  const float* Wih  = (const float*)d_in[3];
  const float* Whh  = (const float*)d_in[4];
  const float* bih  = (const float*)d_in[5];
  const float* bhh  = (const float*)d_in[6];
  const float* Wh2o = (const float*)d_in[7];
  const float* bh2o = (const float*)d_in[8];
  const float* h0   = (const float*)d_in[9];
  const float* c0   = (const float*)d_in[10];
  float* outF = (float*)d_out;

  size_t off = 0;
  auto nb = [&](size_t bytes) { size_t r = off; off += (bytes + 255) & ~(size_t)255; return r; };
  unsigned short* xbf   = (unsigned short*)((char*)d_ws + nb((size_t)B_ * T_ * H_ * 2));  // t-major
  unsigned short* seqA  = (unsigned short*)((char*)d_ws + nb((size_t)B_ * T_ * H_ * 2));
  unsigned short* xgs   = (unsigned short*)((char*)d_ws + nb((size_t)B_ * T_ * 4 * H_ * 2));
  unsigned short* Wihb  = (unsigned short*)((char*)d_ws + nb((size_t)L_ * 4 * H_ * H_ * 2));
  unsigned short* Wh2ob = (unsigned short*)((char*)d_ws + nb((size_t)AS_ * H_ * 2));
  unsigned short* Wt    = (unsigned short*)((char*)d_ws + nb((size_t)AS_ * H_ * 2));
  float*          bsum  = (float*)((char*)d_ws + nb((size_t)L_ * 4 * H_ * 4));
  unsigned short* h_pp  = (unsigned short*)((char*)d_ws + nb((size_t)2 * B_ * H_ * 2));
  unsigned*       slt   = (unsigned*)((char*)d_ws + nb((size_t)L_ * 4096 * 4));
  (void)ws_size; (void)in_sizes; (void)n_in; (void)out_size;

  const int WLAYER = 4 * H_ * H_;
  const int nzero = L_ * 4096;
  const int nprep = nzero + 2 * AS_ * H_ + L_ * WLAYER + L_ * 4 * H_;

  k_prep<<<(nprep + 255) / 256, 256, 0, stream>>>(
      slt, nzero, Wi2h, bi2h, Wt, Wih, Wihb, L_ * WLAYER, Wh2o, Wh2ob, bih, bhh, bsum);
  k_gather<<<B_ * T_, 128, 0, stream>>>(seq, Wt, xbf);

  // layer-0 xg GEMM (cached stores; flushed at dispatch boundary — R14-proven)
  k_gemm<2><<<dim3(B_ * T_ / 128, 4 * H_ / 128), 256, 0, stream>>>(
      xbf, Wihb, bsum, (void*)xgs, B_ * T_, 4 * H_, H_);

  float* hT_base = outF + (size_t)B_ * T_ * AS_;
  float* cT_base = hT_base + (size_t)L_ * B_ * H_;

  // K1: scan(0) + workers {out-GEMM tile, xg1 gated}; out_seq -> seqA (t-major)
  k_fused<<<256, 256, 0, stream>>>(
      xgs, Whh, h_pp, seqA,
      hT_base, cT_base, h0, c0, slt,
      Wihb + (size_t)1 * WLAYER, bsum + (size_t)1 * 4 * H_, xgs,
      xbf, Wh2ob, bh2o, outF);

  // K2: scan(1) + workers {xg2 gated}; out_seq -> xbf (t-major)
  k_fused<<<256, 256, 0, stream>>>(
      xgs, Whh + (size_t)1 * WLAYER, h_pp, xbf,
      hT_base + (size_t)B_ * H_, cT_base + (size_t)B_ * H_,
      h0 + (size_t)B_ * H_, c0 + (size_t)B_ * H_, slt + (size_t)4096,
      Wihb + (size_t)2 * WLAYER, bsum + (size_t)2 * 4 * H_, xgs,
      nullptr, nullptr, nullptr, nullptr);

  // K3: scan(2) only
  k_fused<<<128, 256, 0, stream>>>(
      xgs, Whh + (size_t)2 * WLAYER, h_pp, nullptr,
      hT_base + (size_t)2 * B_ * H_, cT_base + (size_t)2 * B_ * H_,
      h0 + (size_t)2 * B_ * H_, c0 + (size_t)2 * B_ * H_, slt + (size_t)2 * 4096,
      nullptr, nullptr, nullptr, nullptr, nullptr, nullptr, nullptr);
}

// Round 18
// 3311.326 us; speedup vs baseline: 1.0685x; 1.0428x over previous
//
#include <hip/hip_runtime.h>
#include <stdint.h>
#include <stddef.h>

#define B_  64
#define T_  256
#define H_  1024
#define AS_ 128
#define L_  3

typedef __attribute__((ext_vector_type(8))) short bf16x8;
typedef __attribute__((ext_vector_type(4))) float f32x4;
typedef __attribute__((ext_vector_type(4))) unsigned u32x4;

__device__ __forceinline__ unsigned short f2bf(float f) {
  union { float f; unsigned u; } x; x.f = f;
  unsigned r = x.u + 0x7fffu + ((x.u >> 16) & 1u);   // RNE
  return (unsigned short)(r >> 16);
}
__device__ __forceinline__ float bf2f(unsigned short s) {
  union { unsigned u; float f; } x; x.u = ((unsigned)s) << 16; return x.f;
}
__device__ __forceinline__ float sigmf(float x) { return 1.0f / (1.0f + __expf(-x)); }
__device__ __forceinline__ float tanh_f(float x) {
  x = fminf(fmaxf(x, -15.0f), 15.0f);
  float e = __expf(2.0f * x);
  return (e - 1.0f) / (e + 1.0f);
}

// ---- device-coherent (MALL) accessors: relaxed agent atomics — proven R2..R16 ----
__device__ __forceinline__ void st_u16_cc(unsigned short* p, unsigned short v) {
  __hip_atomic_store(p, v, __ATOMIC_RELAXED, __HIP_MEMORY_SCOPE_AGENT);
}
__device__ __forceinline__ void st_u32_cc(unsigned* p, unsigned v) {
  __hip_atomic_store(p, v, __ATOMIC_RELAXED, __HIP_MEMORY_SCOPE_AGENT);
}
__device__ __forceinline__ unsigned ld_u32_cc(const unsigned* p) {
  return __hip_atomic_load(p, __ATOMIC_RELAXED, __HIP_MEMORY_SCOPE_AGENT);
}
// full-bypass loads/stores, no wait — proven R11/R13/R14
__device__ __forceinline__ u32x4 ld_b128_cc_nw(const void* p) {
  u32x4 r;
  asm volatile("global_load_dwordx4 %0, %1, off sc0 sc1" : "=v"(r) : "v"(p));
  return r;
}
__device__ __forceinline__ void st_b128_cc_nw(void* p, u32x4 v) {
  asm volatile("global_store_dwordx4 %0, %1, off sc0 sc1" :: "v"(p), "v"(v) : "memory");
}
// counted waits with tied operands (rule #18)
__device__ __forceinline__ void wait_vm4_tie4(u32x4& a, u32x4& b, u32x4& c, u32x4& d) {
  asm volatile("s_waitcnt vmcnt(4)"
               : "+v"(a), "+v"(b), "+v"(c), "+v"(d) :: "memory");
  __builtin_amdgcn_sched_barrier(0);
}
__device__ __forceinline__ void wait_vm0_tie4(u32x4& a, u32x4& b, u32x4& c, u32x4& d) {
  asm volatile("s_waitcnt vmcnt(0)"
               : "+v"(a), "+v"(b), "+v"(c), "+v"(d) :: "memory");
  __builtin_amdgcn_sched_barrier(0);
}
// LDS-only barrier: keeps outstanding global loads in flight across it
__device__ __forceinline__ void lds_barrier() {
  __builtin_amdgcn_sched_barrier(0);
  asm volatile("s_waitcnt lgkmcnt(0)" ::: "memory");
  __builtin_amdgcn_sched_barrier(0);
  __builtin_amdgcn_s_barrier();
  __builtin_amdgcn_sched_barrier(0);
}

// ---------------- merged prep kernel ----------------
// segments: [zero slots] [Wt] [Wihb f2b] [Wh2ob f2b] [bsum]

__global__ void k_prep(unsigned* __restrict__ zp, int nzero,
                       const float* __restrict__ Wi2h, const float* __restrict__ bi2h,
                       unsigned short* __restrict__ Wt,
                       const float* __restrict__ Wih, unsigned short* __restrict__ Wihb, int nwih,
                       const float* __restrict__ Wh2o, unsigned short* __restrict__ Wh2ob,
                       const float* __restrict__ bih, const float* __restrict__ bhh,
                       float* __restrict__ bsum) {
  int i = blockIdx.x * 256 + threadIdx.x;
  if (i < nzero) { st_u32_cc(zp + i, 0u); return; }
  i -= nzero;
  if (i < AS_ * H_) { int a = i >> 10, h = i & 1023; Wt[i] = f2bf(Wi2h[h * AS_ + a] + bi2h[h]); return; }
  i -= AS_ * H_;
  if (i < nwih) { Wihb[i] = f2bf(Wih[i]); return; }
  i -= nwih;
  if (i < AS_ * H_) { Wh2ob[i] = f2bf(Wh2o[i]); return; }
  i -= AS_ * H_;
  if (i < L_ * 4 * H_) bsum[i] = bih[i] + bhh[i];
}

// ---------------- shared MFMA GEMM tile body ----------------
// OUT codes:
//   2 = bf16 scan-native (A t-major, row = t*64+b), cached stores
//   5 = bf16 gate-table: C idx = row*4096 + ((col&1023)<<2) + (col>>10)
//   6 = f32 plain row-major [M][N]

__device__ __forceinline__ void gld16(const void* g, void* l) {
  __builtin_amdgcn_global_load_lds((const __attribute__((address_space(1))) unsigned int*)g,
                                   (__attribute__((address_space(3))) unsigned int*)l,
                                   16, 0, 0);
}

template <int OUT>
__device__ __forceinline__ void gemm_tile(const unsigned short* __restrict__ A,
                                          const unsigned short* __restrict__ Bm,
                                          const float* __restrict__ bias,
                                          void* __restrict__ Cout,
                                          int m0, int n0, int K, int N, int tid,
                                          unsigned short* As, unsigned short* Bs) {
  const int lane = tid & 63, wv = tid >> 6;
  const int wr = wv >> 1, wc = wv & 1;
  const int kg = lane >> 4, li = lane & 15;
  f32x4 acc[4][4] = {};

  for (int k0 = 0; k0 < K; k0 += 32) {
    for (int i = 0; i < 2; ++i) {
      int c0 = i * 256 + wv * 64;
      int cid = c0 + lane;
      int row = cid >> 2, lc = cid & 3;
      int sc = lc ^ ((row >> 1) & 3);
      gld16(A + (size_t)(m0 + row) * K + k0 + sc * 8, (char*)As + (size_t)c0 * 16);
      gld16(Bm + (size_t)(n0 + row) * K + k0 + sc * 8, (char*)Bs + (size_t)c0 * 16);
    }
    __syncthreads();
    bf16x8 af[4], bfm[4];
#pragma unroll
    for (int mi = 0; mi < 4; ++mi) {
      int row = wr * 64 + mi * 16 + li;
      int pc = kg ^ ((row >> 1) & 3);
      af[mi] = *(const bf16x8*)((const char*)As + row * 64 + pc * 16);
    }
#pragma unroll
    for (int ni = 0; ni < 4; ++ni) {
      int row = wc * 64 + ni * 16 + li;
      int pc = kg ^ ((row >> 1) & 3);
      bfm[ni] = *(const bf16x8*)((const char*)Bs + row * 64 + pc * 16);
    }
#pragma unroll
    for (int mi = 0; mi < 4; ++mi)
#pragma unroll
      for (int ni = 0; ni < 4; ++ni)
        acc[mi][ni] = __builtin_amdgcn_mfma_f32_16x16x32_bf16(af[mi], bfm[ni], acc[mi][ni], 0, 0, 0);
    __syncthreads();
  }

#pragma unroll
  for (int mi = 0; mi < 4; ++mi)
#pragma unroll
    for (int ni = 0; ni < 4; ++ni)
#pragma unroll
      for (int r = 0; r < 4; ++r) {
        int row = m0 + wr * 64 + mi * 16 + kg * 4 + r;
        int col = n0 + wc * 64 + ni * 16 + li;
        float v = acc[mi][ni][r] + bias[col];
        if (OUT == 6) {
          ((float*)Cout)[(size_t)row * N + col] = v;
        } else if (OUT == 5) {
          ((unsigned short*)Cout)[(size_t)row * 4096 + ((col & 1023) << 2) + (col >> 10)] = f2bf(v);
        } else {
          int tt = row >> 6, b = row & 63;     // A is t-major
          int g = col >> 10, u = col & 1023;
          int idx = ((tt * 4 + (b >> 4)) << 16) | ((u >> 5) << 11) |
                    ((b & 15) << 7) | ((u & 31) << 2) | g;
          ((unsigned short*)Cout)[idx] = f2bf(v);
        }
      }
}

template <int OUT>
__global__ __launch_bounds__(256) void k_gemm(const unsigned short* __restrict__ A,
                                              const unsigned short* __restrict__ Bm,
                                              const float* __restrict__ bias,
                                              void* __restrict__ Cout,
                                              int M, int N, int K) {
  __shared__ __align__(16) unsigned short As[128 * 32];
  __shared__ __align__(16) unsigned short Bs[128 * 32];
  gemm_tile<OUT>(A, Bm, bias, Cout, blockIdx.x * 128, blockIdx.y * 128,
                 K, N, threadIdx.x, As, Bs);
}

// ---------------- gather2: one-hot -> xg0 (scan-native, via Tg) + out (via To) ----------------
// x[b,t] = Wt[idx] exactly, so xg0[b,t] = Tg[idx] and out[b,t] = To[idx] (tables bias-folded).
// Each thread moves 64B: ug = tid>>2 in [0,32), q = tid&3 -> 128 x 64B = full 8KB row.

__global__ __launch_bounds__(128) void k_gather2(const float* __restrict__ seq,
                                                 const unsigned short* __restrict__ Tg, // [AS][4096] bf16
                                                 const float* __restrict__ To,          // [AS][AS] f32
                                                 unsigned short* __restrict__ xgs,
                                                 float* __restrict__ outF) {
  __shared__ int sidx;
  const int bt = blockIdx.x, tid = threadIdx.x;
  if (seq[(size_t)bt * AS_ + tid] > 0.5f) sidx = tid;
  __syncthreads();
  const int b = bt >> 8, t = bt & 255;
  outF[(size_t)bt * AS_ + tid] = To[sidx * AS_ + tid];
  const int ug = tid >> 2, q = tid & 3;
  const char* src = (const char*)Tg + (size_t)sidx * 8192 + ug * 256 + q * 64;
  char* dst = (char*)xgs + 2 * ((((size_t)t * 4 + (b >> 4)) << 16) | (ug << 11) | ((b & 15) << 7)) + q * 64;
  ((uint4*)dst)[0] = ((const uint4*)src)[0];
  ((uint4*)dst)[1] = ((const uint4*)src)[1];
  ((uint4*)dst)[2] = ((const uint4*)src)[2];
  ((uint4*)dst)[3] = ((const uint4*)src)[3];
}

// ---------------- fused: scan (wgs 0..127) + persistent GEMM workers (128..255) ----------------
// Workers: 32 xg(l+1) tiles gated on scan slots (R14). Scan = R13 step; out_seq t-major,
// bypass-written BEFORE the slot drain so slot t+2 certifies rows <= t visible.
// 256 wgs at 160KB LDS = 1 wg/CU -> all co-resident, no dispatch-order deadlock.

__global__ __launch_bounds__(256, 1) void k_fused(
    const unsigned short* __restrict__ xgs,   // scan input (scan-native)
    const float* __restrict__ Whh,            // layer-l W_hh f32
    unsigned short* __restrict__ h_pp,        // [2][B][H] bf16 (MALL)
    unsigned short* __restrict__ out_seq,     // [T][B][H] bf16 t-major, or null; gw A
    float* __restrict__ hT, float* __restrict__ cT,
    const float* __restrict__ h0, const float* __restrict__ c0,
    unsigned* __restrict__ slots,             // [4][32][32] layer l
    const unsigned short* __restrict__ WihbN, // layer l+1 W_ih or null
    const float* __restrict__ bsumN,
    unsigned short* __restrict__ xgs_out) {   // gw output (= xgs, in-place)
  __shared__ __align__(16) unsigned short Wlds[64 * 1024];   // 128 KB
  __shared__ __align__(16) unsigned short Hs[16 * 1024];     // 32 KB
  const int tid = threadIdx.x, lane = tid & 63, w = tid >> 6;
  const int wg = blockIdx.x;

  if (wg >= 128) {
    const int Wp = wg - 128;
    unsigned short* As = Wlds;
    unsigned short* Bs = Wlds + 4096;
    if (WihbN) {
      const int pline = (Wp & 31) * 32;
      for (int k = 0; k < 32; ++k) {
        const int gidx = Wp + k * 128;
        const int mt = gidx >> 5, nt = gidx & 31;
        const unsigned tgt = (unsigned)(2 * mt + 3);
        if (w == 0) {                         // poll 128 slots: gb=lane>>4, 2 producers/lane
          const unsigned* base = slots + (lane >> 4) * 1024 + pline + (lane & 15);
          unsigned v0, v1;
          do {
            __builtin_amdgcn_s_sleep(4);
            v0 = ld_u32_cc(base);
            v1 = ld_u32_cc(base + 16);
          } while (__any((int)((v0 < tgt) | (v1 < tgt))));
        }
        __syncthreads();
        gemm_tile<2>(out_seq, WihbN, bsumN, (void*)xgs_out,
                     mt * 128, nt * 128, H_, 4 * H_, tid, As, Bs);
      }
    }
    return;
  }

  // ---------------- scan path (R13/R14) ----------------
  const int gb = wg >> 5, ug = wg & 31;
  const int li = lane & 15, kq = lane >> 4;
  const int b  = gb * 16 + li;
  const int u0 = ug * 32 + w * 8 + kq;
  const int u1 = u0 + 4;

  st_u16_cc(&h_pp[((size_t)B_ + b) * H_ + u0], f2bf(h0[(size_t)b * H_ + u0]));
  st_u16_cc(&h_pp[((size_t)B_ + b) * H_ + u1], f2bf(h0[(size_t)b * H_ + u1]));

  bf16x8 afr[32];
  {
    const int r0 = w * 32 + li;
    const float* wr = Whh + ((size_t)(r0 & 3) * H_ + ug * 32 + (r0 >> 2)) * H_ + kq * 8;
#pragma unroll
    for (int ks = 0; ks < 32; ++ks) {
      const float4 f0 = *(const float4*)(wr + ks * 32);
      const float4 f1 = *(const float4*)(wr + ks * 32 + 4);
      union { ushort4 a[2]; bf16x8 v; } uu_;
      uu_.a[0] = ushort4{f2bf(f0.x), f2bf(f0.y), f2bf(f0.z), f2bf(f0.w)};
      uu_.a[1] = ushort4{f2bf(f1.x), f2bf(f1.y), f2bf(f1.z), f2bf(f1.w)};
      afr[ks] = uu_.v;
    }
  }
  for (int it = 0; it < 16; ++it) {
    const int r = w * 32 + 16 + it;
    const float* wr = Whh + ((size_t)(r & 3) * H_ + ug * 32 + (r >> 2)) * H_;
#pragma unroll
    for (int j = 0; j < 4; ++j) {
      const float4 f = *(const float4*)(wr + lane * 16 + j * 4);
      ushort4 p = ushort4{f2bf(f.x), f2bf(f.y), f2bf(f.z), f2bf(f.w)};
      const int k = lane * 16 + j * 4;
      *(ushort4*)((char*)Wlds + (size_t)(w * 16 + it) * 2048 + ((2 * k) ^ ((it & 7) << 4))) = p;
    }
  }
  float cs0 = c0[(size_t)b * H_ + u0], cs1 = c0[(size_t)b * H_ + u1];
  __syncthreads();
  if (w == 3 && lane < 32) {
    st_u32_cc(&slots[gb * 1024 + lane * 32 + ug], 1u);
    asm volatile("s_waitcnt vmcnt(0)" ::: "memory");
  }

  const char* hbase = (const char*)Hs + (size_t)li * 2048;
  const char* wlb   = (const char*)Wlds + (size_t)(w * 16 + li) * 2048;
  const int fxor = (li & 7) << 4;
  const int sb = tid >> 4, seg = tid & 15;
  const int sswz = (sb & 7) << 4;
  char* drow = (char*)Hs + (size_t)sb * 2048;
  unsigned short* exch = Hs;
  const unsigned* myline = slots + gb * 1024 + ug * 32;

  for (int t = 0; t < T_; ++t) {
    // xv: cached loads (xgs produced by prior dispatch's cached stores)
    const size_t xb2 = ((((size_t)t * 4 + gb) << 16) | (ug << 11) | (li << 7) |
                        ((w * 8 + kq) << 2)) * 2;
    const ushort4 xa = *(const ushort4*)((const char*)xgs + xb2);
    const ushort4 xb = *(const ushort4*)((const char*)xgs + xb2 + 32);

    if (w == 0) {
      const unsigned tgt = (unsigned)(t + 1);
      unsigned v;
      do {
        __builtin_amdgcn_s_sleep(1);
        v = ld_u32_cc(&myline[lane & 31]);
      } while (__any((int)(v < tgt)));
    }
    __syncthreads();

    // split-half bulk: coalesced 16B bypass loads, B half overlaps MFMA-A
    const char* srcrow = (const char*)(h_pp + (size_t)((t & 1) ^ 1) * (B_ * H_) +
                                       (size_t)(gb * 16 + sb) * H_);
    u32x4 A0 = ld_b128_cc_nw(srcrow +   0 * 256 + seg * 16);
    u32x4 A1 = ld_b128_cc_nw(srcrow +   1 * 256 + seg * 16);
    u32x4 A2 = ld_b128_cc_nw(srcrow +   2 * 256 + seg * 16);
    u32x4 A3 = ld_b128_cc_nw(srcrow +   3 * 256 + seg * 16);
    u32x4 B0 = ld_b128_cc_nw(srcrow + 1024 + 0 * 256 + seg * 16);
    u32x4 B1 = ld_b128_cc_nw(srcrow + 1024 + 1 * 256 + seg * 16);
    u32x4 B2 = ld_b128_cc_nw(srcrow + 1024 + 2 * 256 + seg * 16);
    u32x4 B3 = ld_b128_cc_nw(srcrow + 1024 + 3 * 256 + seg * 16);
    wait_vm4_tie4(A0, A1, A2, A3);
    *(u32x4*)(drow + ((0 * 256 + seg * 16) ^ sswz)) = A0;
    *(u32x4*)(drow + ((1 * 256 + seg * 16) ^ sswz)) = A1;
    *(u32x4*)(drow + ((2 * 256 + seg * 16) ^ sswz)) = A2;
    *(u32x4*)(drow + ((3 * 256 + seg * 16) ^ sswz)) = A3;
    lds_barrier();

    f32x4 a0 = {0.f, 0.f, 0.f, 0.f}, a1 = {0.f, 0.f, 0.f, 0.f};
#pragma unroll
    for (int ks = 0; ks < 16; ++ks) {
      const bf16x8 bb = *(const bf16x8*)(hbase + ((ks * 64 + kq * 16) ^ fxor));
      a0 = __builtin_amdgcn_mfma_f32_16x16x32_bf16(afr[ks], bb, a0, 0, 0, 0);
      const bf16x8 aw = *(const bf16x8*)(wlb + ((ks * 64 + kq * 16) ^ fxor));
      a1 = __builtin_amdgcn_mfma_f32_16x16x32_bf16(aw, bb, a1, 0, 0, 0);
    }

    wait_vm0_tie4(B0, B1, B2, B3);
    *(u32x4*)(drow + ((1024 + 0 * 256 + seg * 16) ^ sswz)) = B0;
    *(u32x4*)(drow + ((1024 + 1 * 256 + seg * 16) ^ sswz)) = B1;
    *(u32x4*)(drow + ((1024 + 2 * 256 + seg * 16) ^ sswz)) = B2;
    *(u32x4*)(drow + ((1024 + 3 * 256 + seg * 16) ^ sswz)) = B3;
    lds_barrier();

#pragma unroll
    for (int ks = 16; ks < 32; ++ks) {
      const bf16x8 bb = *(const bf16x8*)(hbase + ((ks * 64 + kq * 16) ^ fxor));
      a0 = __builtin_amdgcn_mfma_f32_16x16x32_bf16(afr[ks], bb, a0, 0, 0, 0);
      const bf16x8 aw = *(const bf16x8*)(wlb + ((ks * 64 + kq * 16) ^ fxor));
      a1 = __builtin_amdgcn_mfma_f32_16x16x32_bf16(aw, bb, a1, 0, 0, 0);
    }

    float h0v, h1v;
    {
      float gi = a0[0] + bf2f(xa.x), gf = a0[1] + bf2f(xa.y);
      float gg = a0[2] + bf2f(xa.z), go = a0[3] + bf2f(xa.w);
      float ci = sigmf(gf) * cs0 + sigmf(gi) * tanh_f(gg);
      cs0 = ci; h0v = sigmf(go) * tanh_f(ci);
    }
    {
      float gi = a1[0] + bf2f(xb.x), gf = a1[1] + bf2f(xb.y);
      float gg = a1[2] + bf2f(xb.z), go = a1[3] + bf2f(xb.w);
      float ci = sigmf(gf) * cs1 + sigmf(gi) * tanh_f(gg);
      cs1 = ci; h1v = sigmf(go) * tanh_f(ci);
    }
    const unsigned short hb0 = f2bf(h0v), hb1 = f2bf(h1v);

    __syncthreads();                          // all Hs MFMA reads done
    exch[li * 32 + w * 8 + kq]     = hb0;
    exch[li * 32 + w * 8 + kq + 4] = hb1;
    __syncthreads();

    if (t < T_ - 1) {
      const int bl = tid >> 4, j = tid & 15;
      const unsigned pack = (unsigned)exch[bl * 32 + 2 * j] |
                            ((unsigned)exch[bl * 32 + 2 * j + 1] << 16);
      st_u32_cc((unsigned*)&h_pp[((size_t)(t & 1) * B_ + gb * 16 + bl) * H_ + ug * 32 + 2 * j],
                pack);
    } else {
      hT[(size_t)b * H_ + u0] = h0v; hT[(size_t)b * H_ + u1] = h1v;
      cT[(size_t)b * H_ + u0] = cs0; cT[(size_t)b * H_ + u1] = cs1;
    }
    if (out_seq && tid < 64) {
      const int bo = tid >> 2, q = tid & 3;
      st_b128_cc_nw(&out_seq[((size_t)t * B_ + gb * 16 + bo) * H_ + ug * 32 + 8 * q],
                    *(const u32x4*)&exch[bo * 32 + 8 * q]);
    }
    asm volatile("s_waitcnt vmcnt(0)" ::: "memory");
    __syncthreads();                          // all publishes + out_seq ACKed
    if (w == 3 && lane < 32) {
      st_u32_cc(&slots[gb * 1024 + lane * 32 + ug], (unsigned)(t + 2));
      asm volatile("s_waitcnt vmcnt(0)" ::: "memory");
    }
  }
}

// ---------------- launcher ----------------

extern "C" void kernel_launch(void* const* d_in, const int* in_sizes, int n_in,
                              void* d_out, int out_size, void* d_ws, size_t ws_size,
                              hipStream_t stream) {
  const float* seq  = (const float*)d_in[0];
  const float* Wi2h = (const float*)d_in[1];
  const float* bi2h = (const float*)d_in[2];
  const float* Wih  = (const float*)d_in[3];
  const float* Whh  = (const float*)d_in[4];
  const float* bih  = (const float*)d_in[5];
  const float* bhh  = (const float*)d_in[6];
  const float* Wh2o = (const float*)d_in[7];
  const float* bh2o = (const float*)d_in[8];
  const float* h0   = (const float*)d_in[9];
  const float* c0   = (const float*)d_in[10];
  float* outF = (float*)d_out;

  size_t off = 0;
  auto nb = [&](size_t bytes) { size_t r = off; off += (bytes + 255) & ~(size_t)255; return r; };
  unsigned short* bufA  = (unsigned short*)((char*)d_ws + nb((size_t)B_ * T_ * H_ * 2));  // out_seq K2
  unsigned short* seqA  = (unsigned short*)((char*)d_ws + nb((size_t)B_ * T_ * H_ * 2));  // out_seq K1
  unsigned short* xgs   = (unsigned short*)((char*)d_ws + nb((size_t)B_ * T_ * 4 * H_ * 2));
  unsigned short* Wihb  = (unsigned short*)((char*)d_ws + nb((size_t)L_ * 4 * H_ * H_ * 2));
  unsigned short* Wh2ob = (unsigned short*)((char*)d_ws + nb((size_t)AS_ * H_ * 2));
  unsigned short* Wt    = (unsigned short*)((char*)d_ws + nb((size_t)AS_ * H_ * 2));
  float*          bsum  = (float*)((char*)d_ws + nb((size_t)L_ * 4 * H_ * 4));
  unsigned short* h_pp  = (unsigned short*)((char*)d_ws + nb((size_t)2 * B_ * H_ * 2));
  unsigned*       slt   = (unsigned*)((char*)d_ws + nb((size_t)L_ * 4096 * 4));
  unsigned short* Tg    = (unsigned short*)((char*)d_ws + nb((size_t)AS_ * 4096 * 2));    // 1MB
  float*          To    = (float*)((char*)d_ws + nb((size_t)AS_ * AS_ * 4));              // 64KB
  (void)ws_size; (void)in_sizes; (void)n_in; (void)out_size;

  const int WLAYER = 4 * H_ * H_;
  const int nzero = L_ * 4096;
  const int nprep = nzero + 2 * AS_ * H_ + L_ * WLAYER + L_ * 4 * H_;

  k_prep<<<(nprep + 255) / 256, 256, 0, stream>>>(
      slt, nzero, Wi2h, bi2h, Wt, Wih, Wihb, L_ * WLAYER, Wh2o, Wh2ob, bih, bhh, bsum);

  // gate table: Tg[a][u*4+g] = W_ih0 @ Wt[a] + bsum0  (M=128, N=4096, K=1024)
  k_gemm<5><<<dim3(1, 32), 256, 0, stream>>>(Wt, Wihb, bsum, (void*)Tg, AS_, 4 * H_, H_);
  // out table: To[a][o] = Wh2o @ Wt[a] + bh2o  (M=128, N=128, K=1024)
  k_gemm<6><<<dim3(1, 1), 256, 0, stream>>>(Wt, Wh2ob, bh2o, (void*)To, AS_, AS_, H_);

  // gather: xg0 (scan-native) + out, pure table lookups
  k_gather2<<<B_ * T_, 128, 0, stream>>>(seq, Tg, To, xgs, outF);

  float* hT_base = outF + (size_t)B_ * T_ * AS_;
  float* cT_base = hT_base + (size_t)L_ * B_ * H_;

  // K1: scan(0) + workers {xg1 gated}; out_seq -> seqA (t-major)
  k_fused<<<256, 256, 0, stream>>>(
      xgs, Whh, h_pp, seqA,
      hT_base, cT_base, h0, c0, slt,
      Wihb + (size_t)1 * WLAYER, bsum + (size_t)1 * 4 * H_, xgs);

  // K2: scan(1) + workers {xg2 gated}; out_seq -> bufA (t-major)
  k_fused<<<256, 256, 0, stream>>>(
      xgs, Whh + (size_t)1 * WLAYER, h_pp, bufA,
      hT_base + (size_t)B_ * H_, cT_base + (size_t)B_ * H_,
      h0 + (size_t)B_ * H_, c0 + (size_t)B_ * H_, slt + (size_t)4096,
      Wihb + (size_t)2 * WLAYER, bsum + (size_t)2 * 4 * H_, xgs);

  // K3: scan(2) only
  k_fused<<<128, 256, 0, stream>>>(
      xgs, Whh + (size_t)2 * WLAYER, h_pp, nullptr,
      hT_base + (size_t)2 * B_ * H_, cT_base + (size_t)2 * B_ * H_,
      h0 + (size_t)2 * B_ * H_, c0 + (size_t)2 * B_ * H_, slt + (size_t)2 * 4096,
      nullptr, nullptr, nullptr);
}

// Round 19
// 3232.046 us; speedup vs baseline: 1.0947x; 1.0245x over previous
//
#include <hip/hip_runtime.h>
#include <stdint.h>
#include <stddef.h>

#define B_  64
#define T_  256
#define H_  1024
#define AS_ 128
#define L_  3

typedef __attribute__((ext_vector_type(8))) short bf16x8;
typedef __attribute__((ext_vector_type(4))) float f32x4;
typedef __attribute__((ext_vector_type(4))) unsigned u32x4;

__device__ __forceinline__ unsigned short f2bf(float f) {
  union { float f; unsigned u; } x; x.f = f;
  unsigned r = x.u + 0x7fffu + ((x.u >> 16) & 1u);   // RNE
  return (unsigned short)(r >> 16);
}
__device__ __forceinline__ float bf2f(unsigned short s) {
  union { unsigned u; float f; } x; x.u = ((unsigned)s) << 16; return x.f;
}
__device__ __forceinline__ float sigmf(float x) { return 1.0f / (1.0f + __expf(-x)); }
__device__ __forceinline__ float tanh_f(float x) {
  x = fminf(fmaxf(x, -15.0f), 15.0f);
  float e = __expf(2.0f * x);
  return (e - 1.0f) / (e + 1.0f);
}

// ---- device-coherent (MALL) accessors: relaxed agent atomics — proven R2..R18 ----
__device__ __forceinline__ void st_u16_cc(unsigned short* p, unsigned short v) {
  __hip_atomic_store(p, v, __ATOMIC_RELAXED, __HIP_MEMORY_SCOPE_AGENT);
}
__device__ __forceinline__ void st_u32_cc(unsigned* p, unsigned v) {
  __hip_atomic_store(p, v, __ATOMIC_RELAXED, __HIP_MEMORY_SCOPE_AGENT);
}
__device__ __forceinline__ unsigned ld_u32_cc(const unsigned* p) {
  return __hip_atomic_load(p, __ATOMIC_RELAXED, __HIP_MEMORY_SCOPE_AGENT);
}
// full-bypass loads/stores, no wait — proven R11/R13/R14
__device__ __forceinline__ u32x4 ld_b128_cc_nw(const void* p) {
  u32x4 r;
  asm volatile("global_load_dwordx4 %0, %1, off sc0 sc1" : "=v"(r) : "v"(p));
  return r;
}
__device__ __forceinline__ void st_b128_cc_nw(void* p, u32x4 v) {
  asm volatile("global_store_dwordx4 %0, %1, off sc0 sc1" :: "v"(p), "v"(v) : "memory");
}
// counted waits with tied operands (rule #18)
__device__ __forceinline__ void wait_vm4_tie4(u32x4& a, u32x4& b, u32x4& c, u32x4& d) {
  asm volatile("s_waitcnt vmcnt(4)"
               : "+v"(a), "+v"(b), "+v"(c), "+v"(d) :: "memory");
  __builtin_amdgcn_sched_barrier(0);
}
__device__ __forceinline__ void wait_vm0_tie4(u32x4& a, u32x4& b, u32x4& c, u32x4& d) {
  asm volatile("s_waitcnt vmcnt(0)"
               : "+v"(a), "+v"(b), "+v"(c), "+v"(d) :: "memory");
  __builtin_amdgcn_sched_barrier(0);
}
// LDS-only barrier: keeps outstanding global loads in flight across it
__device__ __forceinline__ void lds_barrier() {
  __builtin_amdgcn_sched_barrier(0);
  asm volatile("s_waitcnt lgkmcnt(0)" ::: "memory");
  __builtin_amdgcn_sched_barrier(0);
  __builtin_amdgcn_s_barrier();
  __builtin_amdgcn_sched_barrier(0);
}

// ---------------- merged prep kernel ----------------
// segments: [zero slots] [Wt] [Wihb f2b] [Wh2ob f2b] [bsum]

__global__ void k_prep(unsigned* __restrict__ zp, int nzero,
                       const float* __restrict__ Wi2h, const float* __restrict__ bi2h,
                       unsigned short* __restrict__ Wt,
                       const float* __restrict__ Wih, unsigned short* __restrict__ Wihb, int nwih,
                       const float* __restrict__ Wh2o, unsigned short* __restrict__ Wh2ob,
                       const float* __restrict__ bih, const float* __restrict__ bhh,
                       float* __restrict__ bsum) {
  int i = blockIdx.x * 256 + threadIdx.x;
  if (i < nzero) { st_u32_cc(zp + i, 0u); return; }
  i -= nzero;
  if (i < AS_ * H_) { int a = i >> 10, h = i & 1023; Wt[i] = f2bf(Wi2h[h * AS_ + a] + bi2h[h]); return; }
  i -= AS_ * H_;
  if (i < nwih) { Wihb[i] = f2bf(Wih[i]); return; }
  i -= nwih;
  if (i < AS_ * H_) { Wh2ob[i] = f2bf(Wh2o[i]); return; }
  i -= AS_ * H_;
  if (i < L_ * 4 * H_) bsum[i] = bih[i] + bhh[i];
}

// ---------------- shared MFMA GEMM tile body ----------------
// OUT codes:
//   2 = bf16 scan-native (A t-major, row = t*64+b), cached stores
//   5 = bf16 gate-table: C idx = row*4096 + ((col&1023)<<2) + (col>>10)
//   6 = f32 plain row-major [M][N]

__device__ __forceinline__ void gld16(const void* g, void* l) {
  __builtin_amdgcn_global_load_lds((const __attribute__((address_space(1))) unsigned int*)g,
                                   (__attribute__((address_space(3))) unsigned int*)l,
                                   16, 0, 0);
}

template <int OUT>
__device__ __forceinline__ void gemm_tile(const unsigned short* __restrict__ A,
                                          const unsigned short* __restrict__ Bm,
                                          const float* __restrict__ bias,
                                          void* __restrict__ Cout,
                                          int m0, int n0, int K, int N, int tid,
                                          unsigned short* As, unsigned short* Bs) {
  const int lane = tid & 63, wv = tid >> 6;
  const int wr = wv >> 1, wc = wv & 1;
  const int kg = lane >> 4, li = lane & 15;
  f32x4 acc[4][4] = {};

  for (int k0 = 0; k0 < K; k0 += 32) {
    for (int i = 0; i < 2; ++i) {
      int c0 = i * 256 + wv * 64;
      int cid = c0 + lane;
      int row = cid >> 2, lc = cid & 3;
      int sc = lc ^ ((row >> 1) & 3);
      gld16(A + (size_t)(m0 + row) * K + k0 + sc * 8, (char*)As + (size_t)c0 * 16);
      gld16(Bm + (size_t)(n0 + row) * K + k0 + sc * 8, (char*)Bs + (size_t)c0 * 16);
    }
    __syncthreads();
    bf16x8 af[4], bfm[4];
#pragma unroll
    for (int mi = 0; mi < 4; ++mi) {
      int row = wr * 64 + mi * 16 + li;
      int pc = kg ^ ((row >> 1) & 3);
      af[mi] = *(const bf16x8*)((const char*)As + row * 64 + pc * 16);
    }
#pragma unroll
    for (int ni = 0; ni < 4; ++ni) {
      int row = wc * 64 + ni * 16 + li;
      int pc = kg ^ ((row >> 1) & 3);
      bfm[ni] = *(const bf16x8*)((const char*)Bs + row * 64 + pc * 16);
    }
#pragma unroll
    for (int mi = 0; mi < 4; ++mi)
#pragma unroll
      for (int ni = 0; ni < 4; ++ni)
        acc[mi][ni] = __builtin_amdgcn_mfma_f32_16x16x32_bf16(af[mi], bfm[ni], acc[mi][ni], 0, 0, 0);
    __syncthreads();
  }

#pragma unroll
  for (int mi = 0; mi < 4; ++mi)
#pragma unroll
    for (int ni = 0; ni < 4; ++ni)
#pragma unroll
      for (int r = 0; r < 4; ++r) {
        int row = m0 + wr * 64 + mi * 16 + kg * 4 + r;
        int col = n0 + wc * 64 + ni * 16 + li;
        float v = acc[mi][ni][r] + bias[col];
        if (OUT == 6) {
          ((float*)Cout)[(size_t)row * N + col] = v;
        } else if (OUT == 5) {
          ((unsigned short*)Cout)[(size_t)row * 4096 + ((col & 1023) << 2) + (col >> 10)] = f2bf(v);
        } else {
          int tt = row >> 6, b = row & 63;     // A is t-major
          int g = col >> 10, u = col & 1023;
          int idx = ((tt * 4 + (b >> 4)) << 16) | ((u >> 5) << 11) |
                    ((b & 15) << 7) | ((u & 31) << 2) | g;
          ((unsigned short*)Cout)[idx] = f2bf(v);
        }
      }
}

template <int OUT>
__global__ __launch_bounds__(256) void k_gemm(const unsigned short* __restrict__ A,
                                              const unsigned short* __restrict__ Bm,
                                              const float* __restrict__ bias,
                                              void* __restrict__ Cout,
                                              int M, int N, int K) {
  __shared__ __align__(16) unsigned short As[128 * 32];
  __shared__ __align__(16) unsigned short Bs[128 * 32];
  gemm_tile<OUT>(A, Bm, bias, Cout, blockIdx.x * 128, blockIdx.y * 128,
                 K, N, threadIdx.x, As, Bs);
}

// ---------------- gather2: one-hot -> xg0 (scan-native, via Tg) + out (via To) ----------------
// x[b,t] = Wt[idx] exactly, so xg0[b,t] = Tg[idx] and out[b,t] = To[idx] (tables bias-folded).
// Each thread moves 64B: ug = tid>>2 in [0,32), q = tid&3 -> 128 x 64B = full 8KB row.

__global__ __launch_bounds__(128) void k_gather2(const float* __restrict__ seq,
                                                 const unsigned short* __restrict__ Tg, // [AS][4096] bf16
                                                 const float* __restrict__ To,          // [AS][AS] f32
                                                 unsigned short* __restrict__ xgs,
                                                 float* __restrict__ outF) {
  __shared__ int sidx;
  const int bt = blockIdx.x, tid = threadIdx.x;
  if (seq[(size_t)bt * AS_ + tid] > 0.5f) sidx = tid;
  __syncthreads();
  const int b = bt >> 8, t = bt & 255;
  outF[(size_t)bt * AS_ + tid] = To[sidx * AS_ + tid];
  const int ug = tid >> 2, q = tid & 3;
  const char* src = (const char*)Tg + (size_t)sidx * 8192 + ug * 256 + q * 64;
  char* dst = (char*)xgs + 2 * ((((size_t)t * 4 + (b >> 4)) << 16) | (ug << 11) | ((b & 15) << 7)) + q * 64;
  ((uint4*)dst)[0] = ((const uint4*)src)[0];
  ((uint4*)dst)[1] = ((const uint4*)src)[1];
  ((uint4*)dst)[2] = ((const uint4*)src)[2];
  ((uint4*)dst)[3] = ((const uint4*)src)[3];
}

// ---------------- fused: scan (wgs 0..127) + persistent GEMM workers (128..255) ----------------
// Workers: 32 xg(l+1) tiles gated on scan slots (R14). Scan = R13 step; out_seq t-major,
// bypass-written BEFORE the slot drain so slot t+2 certifies rows <= t visible.
// h_pp publish is 64 x 16B bypass stores (shares the tid<64 block + drain with out_seq).
// 256 wgs at 160KB LDS = 1 wg/CU -> all co-resident, no dispatch-order deadlock.

__global__ __launch_bounds__(256, 1) void k_fused(
    const unsigned short* __restrict__ xgs,   // scan input (scan-native)
    const float* __restrict__ Whh,            // layer-l W_hh f32
    unsigned short* __restrict__ h_pp,        // [2][B][H] bf16 (MALL)
    unsigned short* __restrict__ out_seq,     // [T][B][H] bf16 t-major, or null; gw A
    float* __restrict__ hT, float* __restrict__ cT,
    const float* __restrict__ h0, const float* __restrict__ c0,
    unsigned* __restrict__ slots,             // [4][32][32] layer l
    const unsigned short* __restrict__ WihbN, // layer l+1 W_ih or null
    const float* __restrict__ bsumN,
    unsigned short* __restrict__ xgs_out) {   // gw output (= xgs, in-place)
  __shared__ __align__(16) unsigned short Wlds[64 * 1024];   // 128 KB
  __shared__ __align__(16) unsigned short Hs[16 * 1024];     // 32 KB
  const int tid = threadIdx.x, lane = tid & 63, w = tid >> 6;
  const int wg = blockIdx.x;

  if (wg >= 128) {
    const int Wp = wg - 128;
    unsigned short* As = Wlds;
    unsigned short* Bs = Wlds + 4096;
    if (WihbN) {
      const int pline = (Wp & 31) * 32;
      for (int k = 0; k < 32; ++k) {
        const int gidx = Wp + k * 128;
        const int mt = gidx >> 5, nt = gidx & 31;
        const unsigned tgt = (unsigned)(2 * mt + 3);
        if (w == 0) {                         // poll 128 slots: gb=lane>>4, 2 producers/lane
          const unsigned* base = slots + (lane >> 4) * 1024 + pline + (lane & 15);
          unsigned v0, v1;
          do {
            __builtin_amdgcn_s_sleep(4);
            v0 = ld_u32_cc(base);
            v1 = ld_u32_cc(base + 16);
          } while (__any((int)((v0 < tgt) | (v1 < tgt))));
        }
        __syncthreads();
        gemm_tile<2>(out_seq, WihbN, bsumN, (void*)xgs_out,
                     mt * 128, nt * 128, H_, 4 * H_, tid, As, Bs);
      }
    }
    return;
  }

  // ---------------- scan path (R13/R14) ----------------
  const int gb = wg >> 5, ug = wg & 31;
  const int li = lane & 15, kq = lane >> 4;
  const int b  = gb * 16 + li;
  const int u0 = ug * 32 + w * 8 + kq;
  const int u1 = u0 + 4;

  st_u16_cc(&h_pp[((size_t)B_ + b) * H_ + u0], f2bf(h0[(size_t)b * H_ + u0]));
  st_u16_cc(&h_pp[((size_t)B_ + b) * H_ + u1], f2bf(h0[(size_t)b * H_ + u1]));

  bf16x8 afr[32];
  {
    const int r0 = w * 32 + li;
    const float* wr = Whh + ((size_t)(r0 & 3) * H_ + ug * 32 + (r0 >> 2)) * H_ + kq * 8;
#pragma unroll
    for (int ks = 0; ks < 32; ++ks) {
      const float4 f0 = *(const float4*)(wr + ks * 32);
      const float4 f1 = *(const float4*)(wr + ks * 32 + 4);
      union { ushort4 a[2]; bf16x8 v; } uu_;
      uu_.a[0] = ushort4{f2bf(f0.x), f2bf(f0.y), f2bf(f0.z), f2bf(f0.w)};
      uu_.a[1] = ushort4{f2bf(f1.x), f2bf(f1.y), f2bf(f1.z), f2bf(f1.w)};
      afr[ks] = uu_.v;
    }
  }
  for (int it = 0; it < 16; ++it) {
    const int r = w * 32 + 16 + it;
    const float* wr = Whh + ((size_t)(r & 3) * H_ + ug * 32 + (r >> 2)) * H_;
#pragma unroll
    for (int j = 0; j < 4; ++j) {
      const float4 f = *(const float4*)(wr + lane * 16 + j * 4);
      ushort4 p = ushort4{f2bf(f.x), f2bf(f.y), f2bf(f.z), f2bf(f.w)};
      const int k = lane * 16 + j * 4;
      *(ushort4*)((char*)Wlds + (size_t)(w * 16 + it) * 2048 + ((2 * k) ^ ((it & 7) << 4))) = p;
    }
  }
  float cs0 = c0[(size_t)b * H_ + u0], cs1 = c0[(size_t)b * H_ + u1];
  __syncthreads();
  if (w == 3 && lane < 32) {
    st_u32_cc(&slots[gb * 1024 + lane * 32 + ug], 1u);
    asm volatile("s_waitcnt vmcnt(0)" ::: "memory");
  }

  const char* hbase = (const char*)Hs + (size_t)li * 2048;
  const char* wlb   = (const char*)Wlds + (size_t)(w * 16 + li) * 2048;
  const int fxor = (li & 7) << 4;
  const int sb = tid >> 4, seg = tid & 15;
  const int sswz = (sb & 7) << 4;
  char* drow = (char*)Hs + (size_t)sb * 2048;
  unsigned short* exch = Hs;
  const unsigned* myline = slots + gb * 1024 + ug * 32;

  for (int t = 0; t < T_; ++t) {
    // xv: cached loads (xgs produced by prior dispatch's cached stores)
    const size_t xb2 = ((((size_t)t * 4 + gb) << 16) | (ug << 11) | (li << 7) |
                        ((w * 8 + kq) << 2)) * 2;
    const ushort4 xa = *(const ushort4*)((const char*)xgs + xb2);
    const ushort4 xb = *(const ushort4*)((const char*)xgs + xb2 + 32);

    if (w == 0) {
      const unsigned tgt = (unsigned)(t + 1);
      unsigned v;
      do {
        __builtin_amdgcn_s_sleep(1);
        v = ld_u32_cc(&myline[lane & 31]);
      } while (__any((int)(v < tgt)));
    }
    __syncthreads();

    // split-half bulk: coalesced 16B bypass loads, B half overlaps MFMA-A
    const char* srcrow = (const char*)(h_pp + (size_t)((t & 1) ^ 1) * (B_ * H_) +
                                       (size_t)(gb * 16 + sb) * H_);
    u32x4 A0 = ld_b128_cc_nw(srcrow +   0 * 256 + seg * 16);
    u32x4 A1 = ld_b128_cc_nw(srcrow +   1 * 256 + seg * 16);
    u32x4 A2 = ld_b128_cc_nw(srcrow +   2 * 256 + seg * 16);
    u32x4 A3 = ld_b128_cc_nw(srcrow +   3 * 256 + seg * 16);
    u32x4 B0 = ld_b128_cc_nw(srcrow + 1024 + 0 * 256 + seg * 16);
    u32x4 B1 = ld_b128_cc_nw(srcrow + 1024 + 1 * 256 + seg * 16);
    u32x4 B2 = ld_b128_cc_nw(srcrow + 1024 + 2 * 256 + seg * 16);
    u32x4 B3 = ld_b128_cc_nw(srcrow + 1024 + 3 * 256 + seg * 16);
    wait_vm4_tie4(A0, A1, A2, A3);
    *(u32x4*)(drow + ((0 * 256 + seg * 16) ^ sswz)) = A0;
    *(u32x4*)(drow + ((1 * 256 + seg * 16) ^ sswz)) = A1;
    *(u32x4*)(drow + ((2 * 256 + seg * 16) ^ sswz)) = A2;
    *(u32x4*)(drow + ((3 * 256 + seg * 16) ^ sswz)) = A3;
    lds_barrier();

    f32x4 a0 = {0.f, 0.f, 0.f, 0.f}, a1 = {0.f, 0.f, 0.f, 0.f};
#pragma unroll
    for (int ks = 0; ks < 16; ++ks) {
      const bf16x8 bb = *(const bf16x8*)(hbase + ((ks * 64 + kq * 16) ^ fxor));
      a0 = __builtin_amdgcn_mfma_f32_16x16x32_bf16(afr[ks], bb, a0, 0, 0, 0);
      const bf16x8 aw = *(const bf16x8*)(wlb + ((ks * 64 + kq * 16) ^ fxor));
      a1 = __builtin_amdgcn_mfma_f32_16x16x32_bf16(aw, bb, a1, 0, 0, 0);
    }

    wait_vm0_tie4(B0, B1, B2, B3);
    *(u32x4*)(drow + ((1024 + 0 * 256 + seg * 16) ^ sswz)) = B0;
    *(u32x4*)(drow + ((1024 + 1 * 256 + seg * 16) ^ sswz)) = B1;
    *(u32x4*)(drow + ((1024 + 2 * 256 + seg * 16) ^ sswz)) = B2;
    *(u32x4*)(drow + ((1024 + 3 * 256 + seg * 16) ^ sswz)) = B3;
    lds_barrier();

#pragma unroll
    for (int ks = 16; ks < 32; ++ks) {
      const bf16x8 bb = *(const bf16x8*)(hbase + ((ks * 64 + kq * 16) ^ fxor));
      a0 = __builtin_amdgcn_mfma_f32_16x16x32_bf16(afr[ks], bb, a0, 0, 0, 0);
      const bf16x8 aw = *(const bf16x8*)(wlb + ((ks * 64 + kq * 16) ^ fxor));
      a1 = __builtin_amdgcn_mfma_f32_16x16x32_bf16(aw, bb, a1, 0, 0, 0);
    }

    float h0v, h1v;
    {
      float gi = a0[0] + bf2f(xa.x), gf = a0[1] + bf2f(xa.y);
      float gg = a0[2] + bf2f(xa.z), go = a0[3] + bf2f(xa.w);
      float ci = sigmf(gf) * cs0 + sigmf(gi) * tanh_f(gg);
      cs0 = ci; h0v = sigmf(go) * tanh_f(ci);
    }
    {
      float gi = a1[0] + bf2f(xb.x), gf = a1[1] + bf2f(xb.y);
      float gg = a1[2] + bf2f(xb.z), go = a1[3] + bf2f(xb.w);
      float ci = sigmf(gf) * cs1 + sigmf(gi) * tanh_f(gg);
      cs1 = ci; h1v = sigmf(go) * tanh_f(ci);
    }
    const unsigned short hb0 = f2bf(h0v), hb1 = f2bf(h1v);

    __syncthreads();                          // all Hs MFMA reads done
    exch[li * 32 + w * 8 + kq]     = hb0;
    exch[li * 32 + w * 8 + kq + 4] = hb1;
    __syncthreads();

    // publish h_pp (16B coalesced bypass, t<T-1) + out_seq from the same exch block
    if (tid < 64) {
      const int bo = tid >> 2, q = tid & 3;
      const u32x4 v = *(const u32x4*)&exch[bo * 32 + 8 * q];
      if (t < T_ - 1)
        st_b128_cc_nw(&h_pp[((size_t)(t & 1) * B_ + gb * 16 + bo) * H_ + ug * 32 + 8 * q], v);
      if (out_seq)
        st_b128_cc_nw(&out_seq[((size_t)t * B_ + gb * 16 + bo) * H_ + ug * 32 + 8 * q], v);
    }
    if (t == T_ - 1) {
      hT[(size_t)b * H_ + u0] = h0v; hT[(size_t)b * H_ + u1] = h1v;
      cT[(size_t)b * H_ + u0] = cs0; cT[(size_t)b * H_ + u1] = cs1;
    }
    asm volatile("s_waitcnt vmcnt(0)" ::: "memory");
    __syncthreads();                          // all publishes + out_seq ACKed
    if (w == 3 && lane < 32) {
      st_u32_cc(&slots[gb * 1024 + lane * 32 + ug], (unsigned)(t + 2));
      asm volatile("s_waitcnt vmcnt(0)" ::: "memory");
    }
  }
}

// ---------------- launcher ----------------

extern "C" void kernel_launch(void* const* d_in, const int* in_sizes, int n_in,
                              void* d_out, int out_size, void* d_ws, size_t ws_size,
                              hipStream_t stream) {
  const float* seq  = (const float*)d_in[0];
  const float* Wi2h = (const float*)d_in[1];
  const float* bi2h = (const float*)d_in[2];
  const float* Wih  = (const float*)d_in[3];
  const float* Whh  = (const float*)d_in[4];
  const float* bih  = (const float*)d_in[5];
  const float* bhh  = (const float*)d_in[6];
  const float* Wh2o = (const float*)d_in[7];
  const float* bh2o = (const float*)d_in[8];
  const float* h0   = (const float*)d_in[9];
  const float* c0   = (const float*)d_in[10];
  float* outF = (float*)d_out;

  size_t off = 0;
  auto nb = [&](size_t bytes) { size_t r = off; off += (bytes + 255) & ~(size_t)255; return r; };
  unsigned short* bufA  = (unsigned short*)((char*)d_ws + nb((size_t)B_ * T_ * H_ * 2));  // out_seq K2
  unsigned short* seqA  = (unsigned short*)((char*)d_ws + nb((size_t)B_ * T_ * H_ * 2));  // out_seq K1
  unsigned short* xgs   = (unsigned short*)((char*)d_ws + nb((size_t)B_ * T_ * 4 * H_ * 2));
  unsigned short* Wihb  = (unsigned short*)((char*)d_ws + nb((size_t)L_ * 4 * H_ * H_ * 2));
  unsigned short* Wh2ob = (unsigned short*)((char*)d_ws + nb((size_t)AS_ * H_ * 2));
  unsigned short* Wt    = (unsigned short*)((char*)d_ws + nb((size_t)AS_ * H_ * 2));
  float*          bsum  = (float*)((char*)d_ws + nb((size_t)L_ * 4 * H_ * 4));
  unsigned short* h_pp  = (unsigned short*)((char*)d_ws + nb((size_t)2 * B_ * H_ * 2));
  unsigned*       slt   = (unsigned*)((char*)d_ws + nb((size_t)L_ * 4096 * 4));
  unsigned short* Tg    = (unsigned short*)((char*)d_ws + nb((size_t)AS_ * 4096 * 2));    // 1MB
  float*          To    = (float*)((char*)d_ws + nb((size_t)AS_ * AS_ * 4));              // 64KB
  (void)ws_size; (void)in_sizes; (void)n_in; (void)out_size;

  const int WLAYER = 4 * H_ * H_;
  const int nzero = L_ * 4096;
  const int nprep = nzero + 2 * AS_ * H_ + L_ * WLAYER + L_ * 4 * H_;

  k_prep<<<(nprep + 255) / 256, 256, 0, stream>>>(
      slt, nzero, Wi2h, bi2h, Wt, Wih, Wihb, L_ * WLAYER, Wh2o, Wh2ob, bih, bhh, bsum);

  // gate table: Tg[a][u*4+g] = W_ih0 @ Wt[a] + bsum0  (M=128, N=4096, K=1024)
  k_gemm<5><<<dim3(1, 32), 256, 0, stream>>>(Wt, Wihb, bsum, (void*)Tg, AS_, 4 * H_, H_);
  // out table: To[a][o] = Wh2o @ Wt[a] + bh2o  (M=128, N=128, K=1024)
  k_gemm<6><<<dim3(1, 1), 256, 0, stream>>>(Wt, Wh2ob, bh2o, (void*)To, AS_, AS_, H_);

  // gather: xg0 (scan-native) + out, pure table lookups
  k_gather2<<<B_ * T_, 128, 0, stream>>>(seq, Tg, To, xgs, outF);

  float* hT_base = outF + (size_t)B_ * T_ * AS_;
  float* cT_base = hT_base + (size_t)L_ * B_ * H_;

  // K1: scan(0) + workers {xg1 gated}; out_seq -> seqA (t-major)
  k_fused<<<256, 256, 0, stream>>>(
      xgs, Whh, h_pp, seqA,
      hT_base, cT_base, h0, c0, slt,
      Wihb + (size_t)1 * WLAYER, bsum + (size_t)1 * 4 * H_, xgs);

  // K2: scan(1) + workers {xg2 gated}; out_seq -> bufA (t-major)
  k_fused<<<256, 256, 0, stream>>>(
      xgs, Whh + (size_t)1 * WLAYER, h_pp, bufA,
      hT_base + (size_t)B_ * H_, cT_base + (size_t)B_ * H_,
      h0 + (size_t)B_ * H_, c0 + (size_t)B_ * H_, slt + (size_t)4096,
      Wihb + (size_t)2 * WLAYER, bsum + (size_t)2 * 4 * H_, xgs);

  // K3: scan(2) only
  k_fused<<<128, 256, 0, stream>>>(
      xgs, Whh + (size_t)2 * WLAYER, h_pp, nullptr,
      hT_base + (size_t)2 * B_ * H_, cT_base + (size_t)2 * B_ * H_,
      h0 + (size_t)2 * B_ * H_, c0 + (size_t)2 * B_ * H_, slt + (size_t)2 * 4096,
      nullptr, nullptr, nullptr);
}